// Round 1
// baseline (456.022 us; speedup 1.0000x reference)
//
#include <hip/hip_runtime.h>

#define LN_EPS 1e-5f

__device__ __forceinline__ float wave_sum(float v) {
#pragma unroll
  for (int o = 32; o > 0; o >>= 1) v += __shfl_xor(v, o, 64);
  return v;
}

// ---------------------------------------------------------------------------
// A: per-head QKV projection. value/key/query [512][64][64] f32 ->
//    vh/kh/qh laid out [T*H][N][16] f32. qh folded with 1/sqrt(C)=0.125.
// grid 512 (n), block 256 (tid = t*4+h)
// ---------------------------------------------------------------------------
__global__ __launch_bounds__(256) void qkv_kernel(
    const float* __restrict__ value, const float* __restrict__ keyt,
    const float* __restrict__ query, const float* __restrict__ Wv,
    const float* __restrict__ Wk, const float* __restrict__ Wq,
    float* __restrict__ vh, float* __restrict__ kh, float* __restrict__ qh) {
  __shared__ float wv[256], wk[256], wq[256];
  const int tid = threadIdx.x;
  wv[tid] = Wv[tid];
  wk[tid] = Wk[tid];
  wq[tid] = Wq[tid] * 0.125f;
  __syncthreads();
  const int n = blockIdx.x;

#define XFORM(SRC, WARR, DST)                                         \
  {                                                                   \
    const float4* p = (const float4*)(SRC + n * 4096 + tid * 16);     \
    float x[16], y[16];                                               \
    *(float4*)(x + 0) = p[0];                                         \
    *(float4*)(x + 4) = p[1];                                         \
    *(float4*)(x + 8) = p[2];                                         \
    *(float4*)(x + 12) = p[3];                                        \
    _Pragma("unroll") for (int d = 0; d < 16; ++d) {                  \
      float acc = 0.f;                                                \
      _Pragma("unroll") for (int e = 0; e < 16; ++e)                  \
          acc = fmaf(WARR[d * 16 + e], x[e], acc);                    \
      y[d] = acc;                                                     \
    }                                                                 \
    float4* o = (float4*)(DST + (tid * 512 + n) * 16);                \
    o[0] = *(float4*)(y + 0);                                         \
    o[1] = *(float4*)(y + 4);                                         \
    o[2] = *(float4*)(y + 8);                                         \
    o[3] = *(float4*)(y + 12);                                        \
  }

  XFORM(value, wv, vh)
  XFORM(keyt, wk, kh)
  XFORM(query, wq, qh)
#undef XFORM
}

// ---------------------------------------------------------------------------
// B: attention per (t,h): S = Q K^T (scaled), softmax over k, @V.
// grid 512 = 2 blocks per th (256 q-rows each), block 256.
// K,V for the (t,h) staged in LDS (64 KB); per-thread online softmax.
// Output attn [N][T][C] f32.
// ---------------------------------------------------------------------------
__global__ __launch_bounds__(256) void attn_kernel(
    const float* __restrict__ qh, const float* __restrict__ kh,
    const float* __restrict__ vh, float* __restrict__ attn) {
  __shared__ float Ks[8192];
  __shared__ float Vs[8192];
  const int th = blockIdx.x >> 1;
  const int tid = threadIdx.x;
  const float* kb = kh + th * 8192;
  const float* vb = vh + th * 8192;
  for (int i = tid * 4; i < 8192; i += 1024) {
    *(float4*)&Ks[i] = *(const float4*)&kb[i];
    *(float4*)&Vs[i] = *(const float4*)&vb[i];
  }
  __syncthreads();
  const int n = ((blockIdx.x & 1) << 8) + tid;
  const float4* qp = (const float4*)(qh + (th * 512 + n) * 16);
  float4 q0 = qp[0], q1 = qp[1], q2 = qp[2], q3 = qp[3];
  float4 a0 = {0.f, 0.f, 0.f, 0.f}, a1 = a0, a2 = a0, a3 = a0;
  float m = -1e30f, l = 0.f;
  for (int k = 0; k < 512; ++k) {
    const float4* kr = (const float4*)&Ks[k * 16];
    float4 k0 = kr[0], k1 = kr[1], k2 = kr[2], k3 = kr[3];
    float d0 = fmaf(q0.w, k0.w, fmaf(q0.z, k0.z, fmaf(q0.y, k0.y, q0.x * k0.x)));
    float d1 = fmaf(q1.w, k1.w, fmaf(q1.z, k1.z, fmaf(q1.y, k1.y, q1.x * k1.x)));
    float d2 = fmaf(q2.w, k2.w, fmaf(q2.z, k2.z, fmaf(q2.y, k2.y, q2.x * k2.x)));
    float d3 = fmaf(q3.w, k3.w, fmaf(q3.z, k3.z, fmaf(q3.y, k3.y, q3.x * k3.x)));
    float s = (d0 + d1) + (d2 + d3);
    if (s > m) {
      float c = __expf(m - s);
      m = s;
      l *= c;
      a0.x *= c; a0.y *= c; a0.z *= c; a0.w *= c;
      a1.x *= c; a1.y *= c; a1.z *= c; a1.w *= c;
      a2.x *= c; a2.y *= c; a2.z *= c; a2.w *= c;
      a3.x *= c; a3.y *= c; a3.z *= c; a3.w *= c;
    }
    float p = __expf(s - m);
    l += p;
    const float4* vr = (const float4*)&Vs[k * 16];
    float4 v0 = vr[0], v1 = vr[1], v2 = vr[2], v3 = vr[3];
    a0.x = fmaf(p, v0.x, a0.x); a0.y = fmaf(p, v0.y, a0.y);
    a0.z = fmaf(p, v0.z, a0.z); a0.w = fmaf(p, v0.w, a0.w);
    a1.x = fmaf(p, v1.x, a1.x); a1.y = fmaf(p, v1.y, a1.y);
    a1.z = fmaf(p, v1.z, a1.z); a1.w = fmaf(p, v1.w, a1.w);
    a2.x = fmaf(p, v2.x, a2.x); a2.y = fmaf(p, v2.y, a2.y);
    a2.z = fmaf(p, v2.z, a2.z); a2.w = fmaf(p, v2.w, a2.w);
    a3.x = fmaf(p, v3.x, a3.x); a3.y = fmaf(p, v3.y, a3.y);
    a3.z = fmaf(p, v3.z, a3.z); a3.w = fmaf(p, v3.w, a3.w);
  }
  const float inv = 1.f / l;
  a0.x *= inv; a0.y *= inv; a0.z *= inv; a0.w *= inv;
  a1.x *= inv; a1.y *= inv; a1.z *= inv; a1.w *= inv;
  a2.x *= inv; a2.y *= inv; a2.z *= inv; a2.w *= inv;
  a3.x *= inv; a3.y *= inv; a3.z *= inv; a3.w *= inv;
  const int t = th >> 2;
  const int h = th & 3;
  float4* op = (float4*)(attn + n * 4096 + t * 64 + h * 16);
  op[0] = a0; op[1] = a1; op[2] = a2; op[3] = a3;
}

// ---------------------------------------------------------------------------
// C: x = LN1(attn @ Wo^T + bo + query). Weight column per lane in VGPRs.
// grid 2048, block 256 (4 waves x 4 rows)
// ---------------------------------------------------------------------------
__global__ __launch_bounds__(256) void row_wo_ln(
    const float* __restrict__ attn, const float* __restrict__ query,
    const float* __restrict__ Wo, const float* __restrict__ bo,
    const float* __restrict__ g1, const float* __restrict__ b1,
    float* __restrict__ xout) {
  __shared__ float xs[4][64];
  const int tid = threadIdx.x, lane = tid & 63, w = tid >> 6;
  float wc[64];
#pragma unroll
  for (int e = 0; e < 16; ++e)
    *(float4*)&wc[e * 4] = *(const float4*)&Wo[lane * 64 + e * 4];
  const float boc = bo[lane], gc = g1[lane], bc = b1[lane];
  const int r0 = blockIdx.x * 16 + w * 4;
  for (int it = 0; it < 4; ++it) {
    const int r = r0 + it;
    xs[w][lane] = attn[r * 64 + lane];
    float acc = 0.f;
#pragma unroll
    for (int e = 0; e < 64; ++e) acc = fmaf(xs[w][e], wc[e], acc);
    float y = acc + boc + query[r * 64 + lane];
    float mean = wave_sum(y) * 0.015625f;
    float d = y - mean;
    float var = wave_sum(d * d) * 0.015625f;
    xout[r * 64 + lane] = d * rsqrtf(var + LN_EPS) * gc + bc;
  }
}

// ---------------------------------------------------------------------------
// row_proj: out = in @ W^T (64x64, no bias). Used for Wg1 (query->Y) and Wg2.
// ---------------------------------------------------------------------------
__global__ __launch_bounds__(256) void row_proj(
    const float* __restrict__ in, const float* __restrict__ W,
    float* __restrict__ out) {
  __shared__ float xs[4][64];
  const int tid = threadIdx.x, lane = tid & 63, w = tid >> 6;
  float wc[64];
#pragma unroll
  for (int e = 0; e < 16; ++e)
    *(float4*)&wc[e * 4] = *(const float4*)&W[lane * 64 + e * 4];
  const int r0 = blockIdx.x * 16 + w * 4;
  for (int it = 0; it < 4; ++it) {
    const int r = r0 + it;
    xs[w][lane] = in[r * 64 + lane];
    float acc = 0.f;
#pragma unroll
    for (int e = 0; e < 64; ++e) acc = fmaf(xs[w][e], wc[e], acc);
    out[r * 64 + lane] = acc;
  }
}

// ---------------------------------------------------------------------------
// J: gated fusion -> d_out
// ---------------------------------------------------------------------------
__global__ __launch_bounds__(256) void row_gate(
    const float* __restrict__ out1, const float* __restrict__ out2,
    const float* __restrict__ Wo1, const float* __restrict__ Wo2,
    const float* __restrict__ bo1, const float* __restrict__ bo2,
    float* __restrict__ dst) {
  __shared__ float xs1[4][64], xs2[4][64];
  const int tid = threadIdx.x, lane = tid & 63, w = tid >> 6;
  float w1[64], w2[64];
#pragma unroll
  for (int e = 0; e < 16; ++e) {
    *(float4*)&w1[e * 4] = *(const float4*)&Wo1[lane * 64 + e * 4];
    *(float4*)&w2[e * 4] = *(const float4*)&Wo2[lane * 64 + e * 4];
  }
  const float bsum = bo1[lane] + bo2[lane];
  const int r0 = blockIdx.x * 16 + w * 4;
  for (int it = 0; it < 4; ++it) {
    const int r = r0 + it;
    float o1 = out1[r * 64 + lane];
    float o2 = out2[r * 64 + lane];
    xs1[w][lane] = o1;
    xs2[w][lane] = o2;
    float acc = bsum;
#pragma unroll
    for (int e = 0; e < 64; ++e) {
      acc = fmaf(xs1[w][e], w1[e], acc);
      acc = fmaf(xs2[w][e], w2[e], acc);
    }
    float g = 1.f / (1.f + __expf(-acc));
    dst[r * 64 + lane] = o2 + g * (o1 - o2);
  }
}

// ---------------------------------------------------------------------------
// adj mean/var: deterministic two-stage reduction
// ---------------------------------------------------------------------------
__global__ __launch_bounds__(256) void adj_part(const float* __restrict__ adj,
                                                float* __restrict__ ps,
                                                float* __restrict__ pss) {
  __shared__ float r1[4], r2[4];
  const int b = blockIdx.x, tid = threadIdx.x;
  float v0 = adj[b * 512 + tid], v1 = adj[b * 512 + 256 + tid];
  float s = v0 + v1;
  float ss = fmaf(v0, v0, v1 * v1);
  s = wave_sum(s);
  ss = wave_sum(ss);
  if ((tid & 63) == 0) { r1[tid >> 6] = s; r2[tid >> 6] = ss; }
  __syncthreads();
  if (tid == 0) {
    ps[b] = r1[0] + r1[1] + r1[2] + r1[3];
    pss[b] = r2[0] + r2[1] + r2[2] + r2[3];
  }
}

__global__ __launch_bounds__(256) void adj_fin(const float* __restrict__ ps,
                                               const float* __restrict__ pss,
                                               float* __restrict__ stats) {
  __shared__ float r1[4], r2[4];
  const int tid = threadIdx.x;
  float s = ps[tid] + ps[tid + 256];
  float ss = pss[tid] + pss[tid + 256];
  s = wave_sum(s);
  ss = wave_sum(ss);
  if ((tid & 63) == 0) { r1[tid >> 6] = s; r2[tid >> 6] = ss; }
  __syncthreads();
  if (tid == 0) {
    stats[0] = r1[0] + r1[1] + r1[2] + r1[3];
    stats[1] = r2[0] + r2[1] + r2[2] + r2[3];
  }
}

// ---------------------------------------------------------------------------
// GEMM: out[512][4096] = norm(adj)[512][512] @ B[512][4096] + bias[col%64]
// 64x64 tiles, 256 threads, 4x4 micro-tile. adj normalized on the fly.
// ---------------------------------------------------------------------------
template <bool RELU>
__global__ __launch_bounds__(256) void gemm_adj(
    const float* __restrict__ adj, const float* __restrict__ stats,
    const float* __restrict__ B, const float* __restrict__ bias,
    float* __restrict__ out) {
  __shared__ float As[32 * 68], Bs[32 * 68];
  const int tid = threadIdx.x;
  const int tx = tid & 15, ty = tid >> 4;
  const int c0 = blockIdx.x * 64, n0 = blockIdx.y * 64;
  const float am = stats[0] * (1.f / 262144.f);
  const float var = stats[1] * (1.f / 262144.f) - am * am;
  const float rs = rsqrtf(var + LN_EPS);
  const int ar = tid >> 2, ak = (tid & 3) * 8;
  const int bk = tid >> 3, bc = (tid & 7) * 8;
  float acc[4][4] = {};
  for (int k0 = 0; k0 < 512; k0 += 32) {
    float4 a0v = *(const float4*)&adj[(n0 + ar) * 512 + k0 + ak];
    float4 a1v = *(const float4*)&adj[(n0 + ar) * 512 + k0 + ak + 4];
    float4 b0v = *(const float4*)&B[(k0 + bk) * 4096 + c0 + bc];
    float4 b1v = *(const float4*)&B[(k0 + bk) * 4096 + c0 + bc + 4];
    As[(ak + 0) * 68 + ar] = (a0v.x - am) * rs;
    As[(ak + 1) * 68 + ar] = (a0v.y - am) * rs;
    As[(ak + 2) * 68 + ar] = (a0v.z - am) * rs;
    As[(ak + 3) * 68 + ar] = (a0v.w - am) * rs;
    As[(ak + 4) * 68 + ar] = (a1v.x - am) * rs;
    As[(ak + 5) * 68 + ar] = (a1v.y - am) * rs;
    As[(ak + 6) * 68 + ar] = (a1v.z - am) * rs;
    As[(ak + 7) * 68 + ar] = (a1v.w - am) * rs;
    *(float4*)&Bs[bk * 68 + bc] = b0v;
    *(float4*)&Bs[bk * 68 + bc + 4] = b1v;
    __syncthreads();
#pragma unroll
    for (int k = 0; k < 32; ++k) {
      float4 a4 = *(float4*)&As[k * 68 + ty * 4];
      float4 b4 = *(float4*)&Bs[k * 68 + tx * 4];
      float a[4] = {a4.x, a4.y, a4.z, a4.w};
      float b[4] = {b4.x, b4.y, b4.z, b4.w};
#pragma unroll
      for (int i = 0; i < 4; ++i)
#pragma unroll
        for (int j = 0; j < 4; ++j) acc[i][j] = fmaf(a[i], b[j], acc[i][j]);
    }
    __syncthreads();
  }
  float4 bias4 = *(const float4*)&bias[tx * 4];
#pragma unroll
  for (int i = 0; i < 4; ++i) {
    float4 o;
    o.x = acc[i][0] + bias4.x;
    o.y = acc[i][1] + bias4.y;
    o.z = acc[i][2] + bias4.z;
    o.w = acc[i][3] + bias4.w;
    if (RELU) {
      o.x = fmaxf(o.x, 0.f); o.y = fmaxf(o.y, 0.f);
      o.z = fmaxf(o.z, 0.f); o.w = fmaxf(o.w, 0.f);
    }
    *(float4*)&out[(n0 + ty * 4 + i) * 4096 + c0 + tx * 4] = o;
  }
}

// ---------------------------------------------------------------------------
// FFN1: hid[32768][256] = relu(x[32768][64] @ Wf1^T + bf1)
// ---------------------------------------------------------------------------
__global__ __launch_bounds__(256) void gemm_ffn1(
    const float* __restrict__ A, const float* __restrict__ W,
    const float* __restrict__ bias, float* __restrict__ out) {
  __shared__ float As[32 * 68], Bs[32 * 68];
  const int tid = threadIdx.x;
  const int tx = tid & 15, ty = tid >> 4;
  const int c0 = blockIdx.x * 64, r0 = blockIdx.y * 64;
  const int ar = tid >> 2, ak = (tid & 3) * 8;
  float acc[4][4] = {};
  for (int k0 = 0; k0 < 64; k0 += 32) {
    float4 a0v = *(const float4*)&A[(r0 + ar) * 64 + k0 + ak];
    float4 a1v = *(const float4*)&A[(r0 + ar) * 64 + k0 + ak + 4];
    float4 w0v = *(const float4*)&W[(c0 + ar) * 64 + k0 + ak];
    float4 w1v = *(const float4*)&W[(c0 + ar) * 64 + k0 + ak + 4];
    As[(ak + 0) * 68 + ar] = a0v.x; As[(ak + 1) * 68 + ar] = a0v.y;
    As[(ak + 2) * 68 + ar] = a0v.z; As[(ak + 3) * 68 + ar] = a0v.w;
    As[(ak + 4) * 68 + ar] = a1v.x; As[(ak + 5) * 68 + ar] = a1v.y;
    As[(ak + 6) * 68 + ar] = a1v.z; As[(ak + 7) * 68 + ar] = a1v.w;
    Bs[(ak + 0) * 68 + ar] = w0v.x; Bs[(ak + 1) * 68 + ar] = w0v.y;
    Bs[(ak + 2) * 68 + ar] = w0v.z; Bs[(ak + 3) * 68 + ar] = w0v.w;
    Bs[(ak + 4) * 68 + ar] = w1v.x; Bs[(ak + 5) * 68 + ar] = w1v.y;
    Bs[(ak + 6) * 68 + ar] = w1v.z; Bs[(ak + 7) * 68 + ar] = w1v.w;
    __syncthreads();
#pragma unroll
    for (int k = 0; k < 32; ++k) {
      float4 a4 = *(float4*)&As[k * 68 + ty * 4];
      float4 b4 = *(float4*)&Bs[k * 68 + tx * 4];
      float a[4] = {a4.x, a4.y, a4.z, a4.w};
      float b[4] = {b4.x, b4.y, b4.z, b4.w};
#pragma unroll
      for (int i = 0; i < 4; ++i)
#pragma unroll
        for (int j = 0; j < 4; ++j) acc[i][j] = fmaf(a[i], b[j], acc[i][j]);
    }
    __syncthreads();
  }
  float4 bias4 = *(const float4*)&bias[c0 + tx * 4];
#pragma unroll
  for (int i = 0; i < 4; ++i) {
    float4 o;
    o.x = fmaxf(acc[i][0] + bias4.x, 0.f);
    o.y = fmaxf(acc[i][1] + bias4.y, 0.f);
    o.z = fmaxf(acc[i][2] + bias4.z, 0.f);
    o.w = fmaxf(acc[i][3] + bias4.w, 0.f);
    *(float4*)&out[(r0 + ty * 4 + i) * 256 + c0 + tx * 4] = o;
  }
}

// ---------------------------------------------------------------------------
// FFN2 + residual + LN2: out1[32768][64] = LN2(hid @ Wf2^T + bf2 + x)
// BN = 64 = full row -> LN fused in epilogue via LDS tile.
// out1 may alias resid (x): each row read before written, rows disjoint.
// ---------------------------------------------------------------------------
__global__ __launch_bounds__(256) void gemm_ffn2_ln(
    const float* __restrict__ A, const float* __restrict__ W,
    const float* __restrict__ bias, const float* __restrict__ resid,
    const float* __restrict__ g2, const float* __restrict__ b2,
    float* __restrict__ out1) {
  __shared__ float sh[64 * 68];
  float* As = sh;
  float* Bs = sh + 32 * 68;
  const int tid = threadIdx.x;
  const int tx = tid & 15, ty = tid >> 4;
  const int r0 = blockIdx.x * 64;
  const int ar = tid >> 2, ak = (tid & 3) * 8;
  float acc[4][4] = {};
  for (int k0 = 0; k0 < 256; k0 += 32) {
    float4 a0v = *(const float4*)&A[(r0 + ar) * 256 + k0 + ak];
    float4 a1v = *(const float4*)&A[(r0 + ar) * 256 + k0 + ak + 4];
    float4 w0v = *(const float4*)&W[ar * 256 + k0 + ak];
    float4 w1v = *(const float4*)&W[ar * 256 + k0 + ak + 4];
    As[(ak + 0) * 68 + ar] = a0v.x; As[(ak + 1) * 68 + ar] = a0v.y;
    As[(ak + 2) * 68 + ar] = a0v.z; As[(ak + 3) * 68 + ar] = a0v.w;
    As[(ak + 4) * 68 + ar] = a1v.x; As[(ak + 5) * 68 + ar] = a1v.y;
    As[(ak + 6) * 68 + ar] = a1v.z; As[(ak + 7) * 68 + ar] = a1v.w;
    Bs[(ak + 0) * 68 + ar] = w0v.x; Bs[(ak + 1) * 68 + ar] = w0v.y;
    Bs[(ak + 2) * 68 + ar] = w0v.z; Bs[(ak + 3) * 68 + ar] = w0v.w;
    Bs[(ak + 4) * 68 + ar] = w1v.x; Bs[(ak + 5) * 68 + ar] = w1v.y;
    Bs[(ak + 6) * 68 + ar] = w1v.z; Bs[(ak + 7) * 68 + ar] = w1v.w;
    __syncthreads();
#pragma unroll
    for (int k = 0; k < 32; ++k) {
      float4 a4 = *(float4*)&As[k * 68 + ty * 4];
      float4 b4 = *(float4*)&Bs[k * 68 + tx * 4];
      float a[4] = {a4.x, a4.y, a4.z, a4.w};
      float b[4] = {b4.x, b4.y, b4.z, b4.w};
#pragma unroll
      for (int i = 0; i < 4; ++i)
#pragma unroll
        for (int j = 0; j < 4; ++j) acc[i][j] = fmaf(a[i], b[j], acc[i][j]);
    }
    __syncthreads();
  }
  float4 bias4 = *(const float4*)&bias[tx * 4];
  float* tile = sh;  // As/Bs dead (loop ends with __syncthreads)
#pragma unroll
  for (int i = 0; i < 4; ++i) {
    tile[(ty * 4 + i) * 68 + tx * 4 + 0] = acc[i][0] + bias4.x;
    tile[(ty * 4 + i) * 68 + tx * 4 + 1] = acc[i][1] + bias4.y;
    tile[(ty * 4 + i) * 68 + tx * 4 + 2] = acc[i][2] + bias4.z;
    tile[(ty * 4 + i) * 68 + tx * 4 + 3] = acc[i][3] + bias4.w;
  }
  __syncthreads();
  const int lane = tid & 63, w = tid >> 6;
  const float gc = g2[lane], bc = b2[lane];
  for (int rr = w; rr < 64; rr += 4) {
    const int r = r0 + rr;
    float y = tile[rr * 68 + lane] + resid[r * 64 + lane];
    float mean = wave_sum(y) * 0.015625f;
    float d = y - mean;
    float var = wave_sum(d * d) * 0.015625f;
    out1[r * 64 + lane] = d * rsqrtf(var + LN_EPS) * gc + bc;
  }
}

// ---------------------------------------------------------------------------
extern "C" void kernel_launch(void* const* d_in, const int* in_sizes, int n_in,
                              void* d_out, int out_size, void* d_ws,
                              size_t ws_size, hipStream_t stream) {
  const float* value = (const float*)d_in[0];
  const float* key_t = (const float*)d_in[1];
  const float* query = (const float*)d_in[2];
  const float* adj = (const float*)d_in[3];
  const float* Wv = (const float*)d_in[4];
  const float* Wk = (const float*)d_in[5];
  const float* Wq = (const float*)d_in[6];
  const float* Wo = (const float*)d_in[7];
  const float* bo = (const float*)d_in[8];
  const float* g1 = (const float*)d_in[9];
  const float* b1 = (const float*)d_in[10];
  const float* g2 = (const float*)d_in[11];
  const float* b2 = (const float*)d_in[12];
  const float* Wf1 = (const float*)d_in[13];
  const float* bf1 = (const float*)d_in[14];
  const float* Wf2 = (const float*)d_in[15];
  const float* bf2 = (const float*)d_in[16];
  const float* Wg1 = (const float*)d_in[17];
  const float* bg1 = (const float*)d_in[18];
  const float* Wg2 = (const float*)d_in[19];
  const float* bg2 = (const float*)d_in[20];
  const float* Wo1 = (const float*)d_in[21];
  const float* bo1 = (const float*)d_in[22];
  const float* Wo2 = (const float*)d_in[23];
  const float* bo2 = (const float*)d_in[24];

  float* ws = (float*)d_ws;
  // layout (floats): [0,2M) qh | [2M,4M) kh | [4M,6M) vh | [6M,8M) attn
  // hid aliases [0,8M); x at [8M,10M) (out1 aliases x); stats after.
  float* qh = ws + 0;
  float* kh = ws + 2097152;
  float* vh = ws + 4194304;
  float* attn = ws + 6291456;
  float* x = ws + 8388608;
  float* hid = ws;        // reuses qh..attn after they are consumed
  float* out1 = x;        // FFN2 epilogue reads resid row then writes same row
  float* Y = kh;          // after attention, kh region is free
  float* Z = vh;
  float* H2 = attn;
  float* out2 = qh;
  float* stats = ws + 10485760;
  float* ps = ws + 10485764;
  float* pss = ws + 10486276;
  float* dst = (float*)d_out;

  qkv_kernel<<<512, 256, 0, stream>>>(value, key_t, query, Wv, Wk, Wq, vh, kh, qh);
  attn_kernel<<<512, 256, 0, stream>>>(qh, kh, vh, attn);
  row_wo_ln<<<2048, 256, 0, stream>>>(attn, query, Wo, bo, g1, b1, x);
  gemm_ffn1<<<dim3(4, 512), 256, 0, stream>>>(x, Wf1, bf1, hid);
  gemm_ffn2_ln<<<512, 256, 0, stream>>>(hid, Wf2, bf2, x, g2, b2, out1);
  adj_part<<<512, 256, 0, stream>>>(adj, ps, pss);
  adj_fin<<<1, 256, 0, stream>>>(ps, pss, stats);
  row_proj<<<2048, 256, 0, stream>>>(query, Wg1, Y);
  gemm_adj<true><<<dim3(64, 8), 256, 0, stream>>>(adj, stats, Y, bg1, Z);
  row_proj<<<2048, 256, 0, stream>>>(Z, Wg2, H2);
  gemm_adj<false><<<dim3(64, 8), 256, 0, stream>>>(adj, stats, H2, bg2, out2);
  row_gate<<<2048, 256, 0, stream>>>(out1, out2, Wo1, Wo2, bo1, bo2, dst);
}

// Round 2
// 361.060 us; speedup vs baseline: 1.2630x; 1.2630x over previous
//
#include <hip/hip_runtime.h>

#define LN_EPS 1e-5f

typedef __attribute__((ext_vector_type(4))) short short4v;
typedef __attribute__((ext_vector_type(4))) float float4v;

__device__ __forceinline__ float wave_sum(float v) {
#pragma unroll
  for (int o = 32; o > 0; o >>= 1) v += __shfl_xor(v, o, 64);
  return v;
}

// round-to-nearest-even f32 -> bf16
__device__ __forceinline__ unsigned short f2b(float f) {
  unsigned int u = __float_as_uint(f);
  u += 0x7fffu + ((u >> 16) & 1u);
  return (unsigned short)(u >> 16);
}

__device__ __forceinline__ float4v mfma_16x16x16_bf16(short4v a, short4v b,
                                                      float4v c) {
#if __has_builtin(__builtin_amdgcn_mfma_f32_16x16x16bf16_1k)
  return __builtin_amdgcn_mfma_f32_16x16x16bf16_1k(a, b, c, 0, 0, 0);
#else
  float4v d;
  asm volatile(
      "v_mfma_f32_16x16x16_bf16 %0, %1, %2, %3\n\ts_nop 7\n\ts_nop 7"
      : "=v"(d)
      : "v"(a), "v"(b), "v"(c));
  return d;
#endif
}

// ---------------------------------------------------------------------------
// QKV projection -> bf16 MFMA-friendly layouts.
//   kh/qh: [th][512 n][16 d] bf16 (qh folded with 1/sqrt(C)=0.125)
//   vt:    [th][16 d][512 n] bf16 (transposed for the PV A-operand)
// grid 256 (th), block 512 (n = tid). Lane reads a full 64B line per tensor.
// ---------------------------------------------------------------------------
__global__ __launch_bounds__(512) void qkv2_kernel(
    const float* __restrict__ value, const float* __restrict__ keyt,
    const float* __restrict__ query, const float* __restrict__ Wv,
    const float* __restrict__ Wk, const float* __restrict__ Wq,
    unsigned short* __restrict__ vt, unsigned short* __restrict__ kh,
    unsigned short* __restrict__ qh) {
  __shared__ __align__(16) float wv[256], wk[256], wq[256];
  const int tid = threadIdx.x;
  if (tid < 256) {
    wv[tid] = Wv[tid];
    wk[tid] = Wk[tid];
    wq[tid] = Wq[tid] * 0.125f;
  }
  __syncthreads();
  const int th = blockIdx.x;
  const int t = th >> 2, h = th & 3;
  const int n = tid;
  const int base = t * 64 + h * 16;

  float y[16];
  unsigned short tmp[16];

#define XFORM(SRC, WARR)                                            \
  {                                                                 \
    const float4* p = (const float4*)(SRC + n * 4096 + base);       \
    float x[16];                                                    \
    *(float4*)(x + 0) = p[0];                                       \
    *(float4*)(x + 4) = p[1];                                       \
    *(float4*)(x + 8) = p[2];                                       \
    *(float4*)(x + 12) = p[3];                                      \
    _Pragma("unroll") for (int d = 0; d < 16; ++d) {                \
      float acc = 0.f;                                              \
      _Pragma("unroll") for (int e4 = 0; e4 < 4; ++e4) {            \
        float4 w4 = *(const float4*)&WARR[d * 16 + e4 * 4];         \
        acc = fmaf(w4.x, x[e4 * 4 + 0], acc);                       \
        acc = fmaf(w4.y, x[e4 * 4 + 1], acc);                       \
        acc = fmaf(w4.z, x[e4 * 4 + 2], acc);                       \
        acc = fmaf(w4.w, x[e4 * 4 + 3], acc);                       \
      }                                                             \
      y[d] = acc;                                                   \
    }                                                               \
  }

  // V -> vt (transposed store, coalesced 128B per d-plane)
  XFORM(value, wv)
#pragma unroll
  for (int d = 0; d < 16; ++d) vt[th * 8192 + d * 512 + n] = f2b(y[d]);

  // K -> kh
  XFORM(keyt, wk)
#pragma unroll
  for (int d = 0; d < 16; ++d) tmp[d] = f2b(y[d]);
  *(int4*)&kh[(th * 512 + n) * 16] = *(int4*)&tmp[0];
  *(int4*)&kh[(th * 512 + n) * 16 + 8] = *(int4*)&tmp[8];

  // Q (scaled) -> qh
  XFORM(query, wq)
#pragma unroll
  for (int d = 0; d < 16; ++d) tmp[d] = f2b(y[d]);
  *(int4*)&qh[(th * 512 + n) * 16] = *(int4*)&tmp[0];
  *(int4*)&qh[(th * 512 + n) * 16 + 8] = *(int4*)&tmp[8];
#undef XFORM
}

// ---------------------------------------------------------------------------
// MFMA attention. Per (t,h): S^T = K @ Q^T (16x16x16 mfma, C rows = k),
// p = exp(s) in-register (|s| < 0.2: no max needed), packed bf16 feeds
// DIRECTLY as B-operand of O^T = V^T @ P^T (C row-groups == B k-groups).
// grid 512 (2 blocks/th), block 256 (4 waves x 64 q-cols).
// Output o: [th][512 q][16 d] f32.
// ---------------------------------------------------------------------------
#define VPAD 536
__global__ __launch_bounds__(256) void attn_mfma(
    const unsigned short* __restrict__ qh, const unsigned short* __restrict__ kh,
    const unsigned short* __restrict__ vt, float* __restrict__ o) {
  __shared__ __align__(16) unsigned short Vs[16 * VPAD];
  const int th = blockIdx.x >> 1;
  const int tid = threadIdx.x;
  // stage V^T [16][512] -> LDS padded rows
  {
    const unsigned short* vb = vt + th * 8192;
#pragma unroll
    for (int it = 0; it < 4; ++it) {
      const int flat = (it * 256 + tid) * 8;
      const int d = flat >> 9, k = flat & 511;
      *(int4*)&Vs[d * VPAD + k] = *(const int4*)&vb[flat];
    }
  }
  __syncthreads();

  const int lane = tid & 15;
  const int quad = (tid >> 4) & 3;
  const int w = tid >> 6;
  const int q0 = ((blockIdx.x & 1) << 8) + w * 64;

  const unsigned short* qbase = qh + th * 8192;
  const unsigned short* kbase = kh + th * 8192;
  short4v qf[4];
#pragma unroll
  for (int ct = 0; ct < 4; ++ct)
    qf[ct] = *(const short4v*)&qbase[(q0 + ct * 16 + lane) * 16 + quad * 4];

  float4v acc[4];
  float l[4];
#pragma unroll
  for (int ct = 0; ct < 4; ++ct) {
    acc[ct].x = 0.f; acc[ct].y = 0.f; acc[ct].z = 0.f; acc[ct].w = 0.f;
    l[ct] = 0.f;
  }
  float4v zero;
  zero.x = 0.f; zero.y = 0.f; zero.z = 0.f; zero.w = 0.f;

  const unsigned short* vrow = &Vs[lane * VPAD];

  for (int kt = 0; kt < 32; ++kt) {
    const short4v kf =
        *(const short4v*)&kbase[(kt * 16 + lane) * 16 + quad * 4];
    const short4v vf = *(const short4v*)&vrow[kt * 16 + quad * 4];
#pragma unroll
    for (int ct = 0; ct < 4; ++ct) {
      float4v s = mfma_16x16x16_bf16(kf, qf[ct], zero);
      float p0 = __expf(s.x);
      float p1 = __expf(s.y);
      float p2 = __expf(s.z);
      float p3 = __expf(s.w);
      l[ct] += (p0 + p1) + (p2 + p3);
      // pack 4 f32 -> 4 bf16 (round-to-nearest via +0x8000, values ~1.0)
      unsigned int u0 = __float_as_uint(p0) + 0x8000u;
      unsigned int u1 = __float_as_uint(p1) + 0x8000u;
      unsigned int u2 = __float_as_uint(p2) + 0x8000u;
      unsigned int u3 = __float_as_uint(p3) + 0x8000u;
      union {
        uint2 u;
        short4v s4;
      } pk;
      pk.u.x = __builtin_amdgcn_perm(u1, u0, 0x07060302u);
      pk.u.y = __builtin_amdgcn_perm(u3, u2, 0x07060302u);
      acc[ct] = mfma_16x16x16_bf16(vf, pk.s4, acc[ct]);
    }
  }

  // per-column softmax denominator: sum partial l across the 4 quads
#pragma unroll
  for (int ct = 0; ct < 4; ++ct) {
    float lt = l[ct];
    lt += __shfl_xor(lt, 16, 64);
    lt += __shfl_xor(lt, 32, 64);
    const float inv = 1.f / lt;
    float4 out;
    out.x = acc[ct].x * inv;
    out.y = acc[ct].y * inv;
    out.z = acc[ct].z * inv;
    out.w = acc[ct].w * inv;
    *(float4*)&o[th * 8192 + (q0 + ct * 16 + lane) * 16 + quad * 4] = out;
  }
}

// ---------------------------------------------------------------------------
// C: x = LN1(o-heads @ Wo^T + bo + query). Reads o in [th][n][16] layout.
// ---------------------------------------------------------------------------
__global__ __launch_bounds__(256) void row_wo_ln(
    const float* __restrict__ o, const float* __restrict__ query,
    const float* __restrict__ Wo, const float* __restrict__ bo,
    const float* __restrict__ g1, const float* __restrict__ b1,
    float* __restrict__ xout) {
  __shared__ float xs[4][64];
  const int tid = threadIdx.x, lane = tid & 63, w = tid >> 6;
  float wc[64];
#pragma unroll
  for (int e = 0; e < 16; ++e)
    *(float4*)&wc[e * 4] = *(const float4*)&Wo[lane * 64 + e * 4];
  const float boc = bo[lane], gc = g1[lane], bc = b1[lane];
  const int hsel = lane >> 4, dsel = lane & 15;
  const int r0 = blockIdx.x * 16 + w * 4;
  for (int it = 0; it < 4; ++it) {
    const int r = r0 + it;
    const int n = r >> 6, t = r & 63;
    xs[w][lane] = o[(t * 4 + hsel) * 8192 + n * 16 + dsel];
    float acc = 0.f;
#pragma unroll
    for (int e = 0; e < 64; ++e) acc = fmaf(xs[w][e], wc[e], acc);
    float y = acc + boc + query[r * 64 + lane];
    float mean = wave_sum(y) * 0.015625f;
    float d = y - mean;
    float var = wave_sum(d * d) * 0.015625f;
    xout[r * 64 + lane] = d * rsqrtf(var + LN_EPS) * gc + bc;
  }
}

// ---------------------------------------------------------------------------
// row_proj: out = in @ W^T (64x64, no bias).
// ---------------------------------------------------------------------------
__global__ __launch_bounds__(256) void row_proj(
    const float* __restrict__ in, const float* __restrict__ W,
    float* __restrict__ out) {
  __shared__ float xs[4][64];
  const int tid = threadIdx.x, lane = tid & 63, w = tid >> 6;
  float wc[64];
#pragma unroll
  for (int e = 0; e < 16; ++e)
    *(float4*)&wc[e * 4] = *(const float4*)&W[lane * 64 + e * 4];
  const int r0 = blockIdx.x * 16 + w * 4;
  for (int it = 0; it < 4; ++it) {
    const int r = r0 + it;
    xs[w][lane] = in[r * 64 + lane];
    float acc = 0.f;
#pragma unroll
    for (int e = 0; e < 64; ++e) acc = fmaf(xs[w][e], wc[e], acc);
    out[r * 64 + lane] = acc;
  }
}

// ---------------------------------------------------------------------------
// J: gated fusion -> d_out
// ---------------------------------------------------------------------------
__global__ __launch_bounds__(256) void row_gate(
    const float* __restrict__ out1, const float* __restrict__ out2,
    const float* __restrict__ Wo1, const float* __restrict__ Wo2,
    const float* __restrict__ bo1, const float* __restrict__ bo2,
    float* __restrict__ dst) {
  __shared__ float xs1[4][64], xs2[4][64];
  const int tid = threadIdx.x, lane = tid & 63, w = tid >> 6;
  float w1[64], w2[64];
#pragma unroll
  for (int e = 0; e < 16; ++e) {
    *(float4*)&w1[e * 4] = *(const float4*)&Wo1[lane * 64 + e * 4];
    *(float4*)&w2[e * 4] = *(const float4*)&Wo2[lane * 64 + e * 4];
  }
  const float bsum = bo1[lane] + bo2[lane];
  const int r0 = blockIdx.x * 16 + w * 4;
  for (int it = 0; it < 4; ++it) {
    const int r = r0 + it;
    float o1 = out1[r * 64 + lane];
    float o2 = out2[r * 64 + lane];
    xs1[w][lane] = o1;
    xs2[w][lane] = o2;
    float acc = bsum;
#pragma unroll
    for (int e = 0; e < 64; ++e) {
      acc = fmaf(xs1[w][e], w1[e], acc);
      acc = fmaf(xs2[w][e], w2[e], acc);
    }
    float g = 1.f / (1.f + __expf(-acc));
    dst[r * 64 + lane] = o2 + g * (o1 - o2);
  }
}

// ---------------------------------------------------------------------------
// adj mean/var: deterministic two-stage reduction
// ---------------------------------------------------------------------------
__global__ __launch_bounds__(256) void adj_part(const float* __restrict__ adj,
                                                float* __restrict__ ps,
                                                float* __restrict__ pss) {
  __shared__ float r1[4], r2[4];
  const int b = blockIdx.x, tid = threadIdx.x;
  float v0 = adj[b * 512 + tid], v1 = adj[b * 512 + 256 + tid];
  float s = v0 + v1;
  float ss = fmaf(v0, v0, v1 * v1);
  s = wave_sum(s);
  ss = wave_sum(ss);
  if ((tid & 63) == 0) { r1[tid >> 6] = s; r2[tid >> 6] = ss; }
  __syncthreads();
  if (tid == 0) {
    ps[b] = r1[0] + r1[1] + r1[2] + r1[3];
    pss[b] = r2[0] + r2[1] + r2[2] + r2[3];
  }
}

__global__ __launch_bounds__(256) void adj_fin(const float* __restrict__ ps,
                                               const float* __restrict__ pss,
                                               float* __restrict__ stats) {
  __shared__ float r1[4], r2[4];
  const int tid = threadIdx.x;
  float s = ps[tid] + ps[tid + 256];
  float ss = pss[tid] + pss[tid + 256];
  s = wave_sum(s);
  ss = wave_sum(ss);
  if ((tid & 63) == 0) { r1[tid >> 6] = s; r2[tid >> 6] = ss; }
  __syncthreads();
  if (tid == 0) {
    stats[0] = r1[0] + r1[1] + r1[2] + r1[3];
    stats[1] = r2[0] + r2[1] + r2[2] + r2[3];
  }
}

// ---------------------------------------------------------------------------
// GEMM: out[512][4096] = norm(adj)[512][512] @ B[512][4096] + bias[col%64]
// ---------------------------------------------------------------------------
template <bool RELU>
__global__ __launch_bounds__(256) void gemm_adj(
    const float* __restrict__ adj, const float* __restrict__ stats,
    const float* __restrict__ B, const float* __restrict__ bias,
    float* __restrict__ out) {
  __shared__ float As[32 * 68], Bs[32 * 68];
  const int tid = threadIdx.x;
  const int tx = tid & 15, ty = tid >> 4;
  const int c0 = blockIdx.x * 64, n0 = blockIdx.y * 64;
  const float am = stats[0] * (1.f / 262144.f);
  const float var = stats[1] * (1.f / 262144.f) - am * am;
  const float rs = rsqrtf(var + LN_EPS);
  const int ar = tid >> 2, ak = (tid & 3) * 8;
  const int bk = tid >> 3, bc = (tid & 7) * 8;
  float acc[4][4] = {};
  for (int k0 = 0; k0 < 512; k0 += 32) {
    float4 a0v = *(const float4*)&adj[(n0 + ar) * 512 + k0 + ak];
    float4 a1v = *(const float4*)&adj[(n0 + ar) * 512 + k0 + ak + 4];
    float4 b0v = *(const float4*)&B[(k0 + bk) * 4096 + c0 + bc];
    float4 b1v = *(const float4*)&B[(k0 + bk) * 4096 + c0 + bc + 4];
    As[(ak + 0) * 68 + ar] = (a0v.x - am) * rs;
    As[(ak + 1) * 68 + ar] = (a0v.y - am) * rs;
    As[(ak + 2) * 68 + ar] = (a0v.z - am) * rs;
    As[(ak + 3) * 68 + ar] = (a0v.w - am) * rs;
    As[(ak + 4) * 68 + ar] = (a1v.x - am) * rs;
    As[(ak + 5) * 68 + ar] = (a1v.y - am) * rs;
    As[(ak + 6) * 68 + ar] = (a1v.z - am) * rs;
    As[(ak + 7) * 68 + ar] = (a1v.w - am) * rs;
    *(float4*)&Bs[bk * 68 + bc] = b0v;
    *(float4*)&Bs[bk * 68 + bc + 4] = b1v;
    __syncthreads();
#pragma unroll
    for (int k = 0; k < 32; ++k) {
      float4 a4 = *(float4*)&As[k * 68 + ty * 4];
      float4 b4 = *(float4*)&Bs[k * 68 + tx * 4];
      float a[4] = {a4.x, a4.y, a4.z, a4.w};
      float b[4] = {b4.x, b4.y, b4.z, b4.w};
#pragma unroll
      for (int i = 0; i < 4; ++i)
#pragma unroll
        for (int j = 0; j < 4; ++j) acc[i][j] = fmaf(a[i], b[j], acc[i][j]);
    }
    __syncthreads();
  }
  float4 bias4 = *(const float4*)&bias[tx * 4];
#pragma unroll
  for (int i = 0; i < 4; ++i) {
    float4 o;
    o.x = acc[i][0] + bias4.x;
    o.y = acc[i][1] + bias4.y;
    o.z = acc[i][2] + bias4.z;
    o.w = acc[i][3] + bias4.w;
    if (RELU) {
      o.x = fmaxf(o.x, 0.f); o.y = fmaxf(o.y, 0.f);
      o.z = fmaxf(o.z, 0.f); o.w = fmaxf(o.w, 0.f);
    }
    *(float4*)&out[(n0 + ty * 4 + i) * 4096 + c0 + tx * 4] = o;
  }
}

// ---------------------------------------------------------------------------
// FFN1: hid[32768][256] = relu(x[32768][64] @ Wf1^T + bf1)
// ---------------------------------------------------------------------------
__global__ __launch_bounds__(256) void gemm_ffn1(
    const float* __restrict__ A, const float* __restrict__ W,
    const float* __restrict__ bias, float* __restrict__ out) {
  __shared__ float As[32 * 68], Bs[32 * 68];
  const int tid = threadIdx.x;
  const int tx = tid & 15, ty = tid >> 4;
  const int c0 = blockIdx.x * 64, r0 = blockIdx.y * 64;
  const int ar = tid >> 2, ak = (tid & 3) * 8;
  float acc[4][4] = {};
  for (int k0 = 0; k0 < 64; k0 += 32) {
    float4 a0v = *(const float4*)&A[(r0 + ar) * 64 + k0 + ak];
    float4 a1v = *(const float4*)&A[(r0 + ar) * 64 + k0 + ak + 4];
    float4 w0v = *(const float4*)&W[(c0 + ar) * 64 + k0 + ak];
    float4 w1v = *(const float4*)&W[(c0 + ar) * 64 + k0 + ak + 4];
    As[(ak + 0) * 68 + ar] = a0v.x; As[(ak + 1) * 68 + ar] = a0v.y;
    As[(ak + 2) * 68 + ar] = a0v.z; As[(ak + 3) * 68 + ar] = a0v.w;
    As[(ak + 4) * 68 + ar] = a1v.x; As[(ak + 5) * 68 + ar] = a1v.y;
    As[(ak + 6) * 68 + ar] = a1v.z; As[(ak + 7) * 68 + ar] = a1v.w;
    Bs[(ak + 0) * 68 + ar] = w0v.x; Bs[(ak + 1) * 68 + ar] = w0v.y;
    Bs[(ak + 2) * 68 + ar] = w0v.z; Bs[(ak + 3) * 68 + ar] = w0v.w;
    Bs[(ak + 4) * 68 + ar] = w1v.x; Bs[(ak + 5) * 68 + ar] = w1v.y;
    Bs[(ak + 6) * 68 + ar] = w1v.z; Bs[(ak + 7) * 68 + ar] = w1v.w;
    __syncthreads();
#pragma unroll
    for (int k = 0; k < 32; ++k) {
      float4 a4 = *(float4*)&As[k * 68 + ty * 4];
      float4 b4 = *(float4*)&Bs[k * 68 + tx * 4];
      float a[4] = {a4.x, a4.y, a4.z, a4.w};
      float b[4] = {b4.x, b4.y, b4.z, b4.w};
#pragma unroll
      for (int i = 0; i < 4; ++i)
#pragma unroll
        for (int j = 0; j < 4; ++j) acc[i][j] = fmaf(a[i], b[j], acc[i][j]);
    }
    __syncthreads();
  }
  float4 bias4 = *(const float4*)&bias[c0 + tx * 4];
#pragma unroll
  for (int i = 0; i < 4; ++i) {
    float4 o;
    o.x = fmaxf(acc[i][0] + bias4.x, 0.f);
    o.y = fmaxf(acc[i][1] + bias4.y, 0.f);
    o.z = fmaxf(acc[i][2] + bias4.z, 0.f);
    o.w = fmaxf(acc[i][3] + bias4.w, 0.f);
    *(float4*)&out[(r0 + ty * 4 + i) * 256 + c0 + tx * 4] = o;
  }
}

// ---------------------------------------------------------------------------
// FFN2 + residual + LN2
// ---------------------------------------------------------------------------
__global__ __launch_bounds__(256) void gemm_ffn2_ln(
    const float* __restrict__ A, const float* __restrict__ W,
    const float* __restrict__ bias, const float* __restrict__ resid,
    const float* __restrict__ g2, const float* __restrict__ b2,
    float* __restrict__ out1) {
  __shared__ float sh[64 * 68];
  float* As = sh;
  float* Bs = sh + 32 * 68;
  const int tid = threadIdx.x;
  const int tx = tid & 15, ty = tid >> 4;
  const int r0 = blockIdx.x * 64;
  const int ar = tid >> 2, ak = (tid & 3) * 8;
  float acc[4][4] = {};
  for (int k0 = 0; k0 < 256; k0 += 32) {
    float4 a0v = *(const float4*)&A[(r0 + ar) * 256 + k0 + ak];
    float4 a1v = *(const float4*)&A[(r0 + ar) * 256 + k0 + ak + 4];
    float4 w0v = *(const float4*)&W[ar * 256 + k0 + ak];
    float4 w1v = *(const float4*)&W[ar * 256 + k0 + ak + 4];
    As[(ak + 0) * 68 + ar] = a0v.x; As[(ak + 1) * 68 + ar] = a0v.y;
    As[(ak + 2) * 68 + ar] = a0v.z; As[(ak + 3) * 68 + ar] = a0v.w;
    As[(ak + 4) * 68 + ar] = a1v.x; As[(ak + 5) * 68 + ar] = a1v.y;
    As[(ak + 6) * 68 + ar] = a1v.z; As[(ak + 7) * 68 + ar] = a1v.w;
    Bs[(ak + 0) * 68 + ar] = w0v.x; Bs[(ak + 1) * 68 + ar] = w0v.y;
    Bs[(ak + 2) * 68 + ar] = w0v.z; Bs[(ak + 3) * 68 + ar] = w0v.w;
    Bs[(ak + 4) * 68 + ar] = w1v.x; Bs[(ak + 5) * 68 + ar] = w1v.y;
    Bs[(ak + 6) * 68 + ar] = w1v.z; Bs[(ak + 7) * 68 + ar] = w1v.w;
    __syncthreads();
#pragma unroll
    for (int k = 0; k < 32; ++k) {
      float4 a4 = *(float4*)&As[k * 68 + ty * 4];
      float4 b4 = *(float4*)&Bs[k * 68 + tx * 4];
      float a[4] = {a4.x, a4.y, a4.z, a4.w};
      float b[4] = {b4.x, b4.y, b4.z, b4.w};
#pragma unroll
      for (int i = 0; i < 4; ++i)
#pragma unroll
        for (int j = 0; j < 4; ++j) acc[i][j] = fmaf(a[i], b[j], acc[i][j]);
    }
    __syncthreads();
  }
  float4 bias4 = *(const float4*)&bias[tx * 4];
  float* tile = sh;
#pragma unroll
  for (int i = 0; i < 4; ++i) {
    tile[(ty * 4 + i) * 68 + tx * 4 + 0] = acc[i][0] + bias4.x;
    tile[(ty * 4 + i) * 68 + tx * 4 + 1] = acc[i][1] + bias4.y;
    tile[(ty * 4 + i) * 68 + tx * 4 + 2] = acc[i][2] + bias4.z;
    tile[(ty * 4 + i) * 68 + tx * 4 + 3] = acc[i][3] + bias4.w;
  }
  __syncthreads();
  const int lane = tid & 63, w = tid >> 6;
  const float gc = g2[lane], bc = b2[lane];
  for (int rr = w; rr < 64; rr += 4) {
    const int r = r0 + rr;
    float y = tile[rr * 68 + lane] + resid[r * 64 + lane];
    float mean = wave_sum(y) * 0.015625f;
    float d = y - mean;
    float var = wave_sum(d * d) * 0.015625f;
    out1[r * 64 + lane] = d * rsqrtf(var + LN_EPS) * gc + bc;
  }
}

// ---------------------------------------------------------------------------
extern "C" void kernel_launch(void* const* d_in, const int* in_sizes, int n_in,
                              void* d_out, int out_size, void* d_ws,
                              size_t ws_size, hipStream_t stream) {
  const float* value = (const float*)d_in[0];
  const float* key_t = (const float*)d_in[1];
  const float* query = (const float*)d_in[2];
  const float* adj = (const float*)d_in[3];
  const float* Wv = (const float*)d_in[4];
  const float* Wk = (const float*)d_in[5];
  const float* Wq = (const float*)d_in[6];
  const float* Wo = (const float*)d_in[7];
  const float* bo = (const float*)d_in[8];
  const float* g1 = (const float*)d_in[9];
  const float* b1 = (const float*)d_in[10];
  const float* g2 = (const float*)d_in[11];
  const float* b2 = (const float*)d_in[12];
  const float* Wf1 = (const float*)d_in[13];
  const float* bf1 = (const float*)d_in[14];
  const float* Wf2 = (const float*)d_in[15];
  const float* bf2 = (const float*)d_in[16];
  const float* Wg1 = (const float*)d_in[17];
  const float* bg1 = (const float*)d_in[18];
  const float* Wg2 = (const float*)d_in[19];
  const float* bg2 = (const float*)d_in[20];
  const float* Wo1 = (const float*)d_in[21];
  const float* bo1 = (const float*)d_in[22];
  const float* Wo2 = (const float*)d_in[23];
  const float* bo2 = (const float*)d_in[24];

  float* ws = (float*)d_ws;
  // f32-unit layout:
  //  [0,1M)   qh bf16      [1M,2M) kh bf16     [2M,3M) vt bf16
  //  [3M,5M)  o f32        [8M,10M) x / out1
  //  hid = [0,8M) (aliases qh..o after consumed)
  //  Y=[0,2M) Z=[2M,4M) H2=[4M,6M) out2=[6M,8M) (after hid dead)
  unsigned short* qh = (unsigned short*)(ws + 0);
  unsigned short* kh = (unsigned short*)(ws + 1048576);
  unsigned short* vt = (unsigned short*)(ws + 2097152);
  float* o = ws + 3145728;
  float* x = ws + 8388608;
  float* hid = ws;
  float* out1 = x;
  float* Y = ws + 0;
  float* Z = ws + 2097152;
  float* H2 = ws + 4194304;
  float* out2 = ws + 6291456;
  float* stats = ws + 10485760;
  float* ps = ws + 10485764;
  float* pss = ws + 10486276;
  float* dst = (float*)d_out;

  qkv2_kernel<<<256, 512, 0, stream>>>(value, key_t, query, Wv, Wk, Wq, vt, kh, qh);
  attn_mfma<<<512, 256, 0, stream>>>(qh, kh, vt, o);
  row_wo_ln<<<2048, 256, 0, stream>>>(o, query, Wo, bo, g1, b1, x);
  gemm_ffn1<<<dim3(4, 512), 256, 0, stream>>>(x, Wf1, bf1, hid);
  gemm_ffn2_ln<<<512, 256, 0, stream>>>(hid, Wf2, bf2, x, g2, b2, out1);
  adj_part<<<512, 256, 0, stream>>>(adj, ps, pss);
  adj_fin<<<1, 256, 0, stream>>>(ps, pss, stats);
  row_proj<<<2048, 256, 0, stream>>>(query, Wg1, Y);
  gemm_adj<true><<<dim3(64, 8), 256, 0, stream>>>(adj, stats, Y, bg1, Z);
  row_proj<<<2048, 256, 0, stream>>>(Z, Wg2, H2);
  gemm_adj<false><<<dim3(64, 8), 256, 0, stream>>>(adj, stats, H2, bg2, out2);
  row_gate<<<2048, 256, 0, stream>>>(out1, out2, Wo1, Wo2, bo1, bo2, dst);
}

// Round 4
// 337.875 us; speedup vs baseline: 1.3497x; 1.0686x over previous
//
#include <hip/hip_runtime.h>

#define LN_EPS 1e-5f

typedef __attribute__((ext_vector_type(4))) short short4v;
typedef __attribute__((ext_vector_type(4))) float float4v;

__device__ __forceinline__ float wave_sum(float v) {
#pragma unroll
  for (int o = 32; o > 0; o >>= 1) v += __shfl_xor(v, o, 64);
  return v;
}

// round-to-nearest-even f32 -> bf16
__device__ __forceinline__ unsigned short f2b(float f) {
  unsigned int u = __float_as_uint(f);
  u += 0x7fffu + ((u >> 16) & 1u);
  return (unsigned short)(u >> 16);
}

__device__ __forceinline__ float b2f(unsigned short h) {
  return __uint_as_float(((unsigned int)h) << 16);
}

__device__ __forceinline__ float4v mfma_16x16x16_bf16(short4v a, short4v b,
                                                      float4v c) {
#if __has_builtin(__builtin_amdgcn_mfma_f32_16x16x16bf16_1k)
  return __builtin_amdgcn_mfma_f32_16x16x16bf16_1k(a, b, c, 0, 0, 0);
#else
  float4v d;
  asm volatile(
      "v_mfma_f32_16x16x16_bf16 %0, %1, %2, %3\n\ts_nop 7\n\ts_nop 7"
      : "=v"(d)
      : "v"(a), "v"(b), "v"(c));
  return d;
#endif
}

// ---------------------------------------------------------------------------
// QKV projection -> bf16 MFMA-friendly layouts.
// ---------------------------------------------------------------------------
__global__ __launch_bounds__(512) void qkv2_kernel(
    const float* __restrict__ value, const float* __restrict__ keyt,
    const float* __restrict__ query, const float* __restrict__ Wv,
    const float* __restrict__ Wk, const float* __restrict__ Wq,
    unsigned short* __restrict__ vt, unsigned short* __restrict__ kh,
    unsigned short* __restrict__ qh) {
  __shared__ __align__(16) float wv[256], wk[256], wq[256];
  const int tid = threadIdx.x;
  if (tid < 256) {
    wv[tid] = Wv[tid];
    wk[tid] = Wk[tid];
    wq[tid] = Wq[tid] * 0.125f;
  }
  __syncthreads();
  const int th = blockIdx.x;
  const int t = th >> 2, h = th & 3;
  const int n = tid;
  const int base = t * 64 + h * 16;

  float y[16];
  unsigned short tmp[16];

#define XFORM(SRC, WARR)                                            \
  {                                                                 \
    const float4* p = (const float4*)(SRC + n * 4096 + base);       \
    float x[16];                                                    \
    *(float4*)(x + 0) = p[0];                                       \
    *(float4*)(x + 4) = p[1];                                       \
    *(float4*)(x + 8) = p[2];                                       \
    *(float4*)(x + 12) = p[3];                                      \
    _Pragma("unroll") for (int d = 0; d < 16; ++d) {                \
      float acc = 0.f;                                              \
      _Pragma("unroll") for (int e4 = 0; e4 < 4; ++e4) {            \
        float4 w4 = *(const float4*)&WARR[d * 16 + e4 * 4];         \
        acc = fmaf(w4.x, x[e4 * 4 + 0], acc);                       \
        acc = fmaf(w4.y, x[e4 * 4 + 1], acc);                       \
        acc = fmaf(w4.z, x[e4 * 4 + 2], acc);                       \
        acc = fmaf(w4.w, x[e4 * 4 + 3], acc);                       \
      }                                                             \
      y[d] = acc;                                                   \
    }                                                               \
  }

  XFORM(value, wv)
#pragma unroll
  for (int d = 0; d < 16; ++d) vt[th * 8192 + d * 512 + n] = f2b(y[d]);

  XFORM(keyt, wk)
#pragma unroll
  for (int d = 0; d < 16; ++d) tmp[d] = f2b(y[d]);
  *(int4*)&kh[(th * 512 + n) * 16] = *(int4*)&tmp[0];
  *(int4*)&kh[(th * 512 + n) * 16 + 8] = *(int4*)&tmp[8];

  XFORM(query, wq)
#pragma unroll
  for (int d = 0; d < 16; ++d) tmp[d] = f2b(y[d]);
  *(int4*)&qh[(th * 512 + n) * 16] = *(int4*)&tmp[0];
  *(int4*)&qh[(th * 512 + n) * 16 + 8] = *(int4*)&tmp[8];
#undef XFORM
}

// ---------------------------------------------------------------------------
// MFMA attention (verified in R2).
// ---------------------------------------------------------------------------
#define VPAD 536
__global__ __launch_bounds__(256) void attn_mfma(
    const unsigned short* __restrict__ qh, const unsigned short* __restrict__ kh,
    const unsigned short* __restrict__ vt, float* __restrict__ o) {
  __shared__ __align__(16) unsigned short Vs[16 * VPAD];
  const int th = blockIdx.x >> 1;
  const int tid = threadIdx.x;
  {
    const unsigned short* vb = vt + th * 8192;
#pragma unroll
    for (int it = 0; it < 4; ++it) {
      const int flat = (it * 256 + tid) * 8;
      const int d = flat >> 9, k = flat & 511;
      *(int4*)&Vs[d * VPAD + k] = *(const int4*)&vb[flat];
    }
  }
  __syncthreads();

  const int lane = tid & 15;
  const int quad = (tid >> 4) & 3;
  const int w = tid >> 6;
  const int q0 = ((blockIdx.x & 1) << 8) + w * 64;

  const unsigned short* qbase = qh + th * 8192;
  const unsigned short* kbase = kh + th * 8192;
  short4v qf[4];
#pragma unroll
  for (int ct = 0; ct < 4; ++ct)
    qf[ct] = *(const short4v*)&qbase[(q0 + ct * 16 + lane) * 16 + quad * 4];

  float4v acc[4];
  float l[4];
#pragma unroll
  for (int ct = 0; ct < 4; ++ct) {
    acc[ct].x = 0.f; acc[ct].y = 0.f; acc[ct].z = 0.f; acc[ct].w = 0.f;
    l[ct] = 0.f;
  }
  float4v zero;
  zero.x = 0.f; zero.y = 0.f; zero.z = 0.f; zero.w = 0.f;

  const unsigned short* vrow = &Vs[lane * VPAD];

  for (int kt = 0; kt < 32; ++kt) {
    const short4v kf =
        *(const short4v*)&kbase[(kt * 16 + lane) * 16 + quad * 4];
    const short4v vf = *(const short4v*)&vrow[kt * 16 + quad * 4];
#pragma unroll
    for (int ct = 0; ct < 4; ++ct) {
      float4v s = mfma_16x16x16_bf16(kf, qf[ct], zero);
      float p0 = __expf(s.x);
      float p1 = __expf(s.y);
      float p2 = __expf(s.z);
      float p3 = __expf(s.w);
      l[ct] += (p0 + p1) + (p2 + p3);
      unsigned int u0 = __float_as_uint(p0) + 0x8000u;
      unsigned int u1 = __float_as_uint(p1) + 0x8000u;
      unsigned int u2 = __float_as_uint(p2) + 0x8000u;
      unsigned int u3 = __float_as_uint(p3) + 0x8000u;
      union {
        uint2 u;
        short4v s4;
      } pk;
      pk.u.x = __builtin_amdgcn_perm(u1, u0, 0x07060302u);
      pk.u.y = __builtin_amdgcn_perm(u3, u2, 0x07060302u);
      acc[ct] = mfma_16x16x16_bf16(vf, pk.s4, acc[ct]);
    }
  }

#pragma unroll
  for (int ct = 0; ct < 4; ++ct) {
    float lt = l[ct];
    lt += __shfl_xor(lt, 16, 64);
    lt += __shfl_xor(lt, 32, 64);
    const float inv = 1.f / lt;
    float4 out;
    out.x = acc[ct].x * inv;
    out.y = acc[ct].y * inv;
    out.z = acc[ct].z * inv;
    out.w = acc[ct].w * inv;
    *(float4*)&o[th * 8192 + (q0 + ct * 16 + lane) * 16 + quad * 4] = out;
  }
}

// ---------------------------------------------------------------------------
// C: x = LN1(o-heads @ Wo^T + bo + query); emits f32 x AND bf16 x.
// ---------------------------------------------------------------------------
__global__ __launch_bounds__(256) void row_wo_ln(
    const float* __restrict__ o, const float* __restrict__ query,
    const float* __restrict__ Wo, const float* __restrict__ bo,
    const float* __restrict__ g1, const float* __restrict__ b1,
    float* __restrict__ xout, unsigned short* __restrict__ xbf) {
  __shared__ float xs[4][64];
  const int tid = threadIdx.x, lane = tid & 63, w = tid >> 6;
  float wc[64];
#pragma unroll
  for (int e = 0; e < 16; ++e)
    *(float4*)&wc[e * 4] = *(const float4*)&Wo[lane * 64 + e * 4];
  const float boc = bo[lane], gc = g1[lane], bc = b1[lane];
  const int hsel = lane >> 4, dsel = lane & 15;
  const int r0 = blockIdx.x * 16 + w * 4;
  for (int it = 0; it < 4; ++it) {
    const int r = r0 + it;
    const int n = r >> 6, t = r & 63;
    xs[w][lane] = o[(t * 4 + hsel) * 8192 + n * 16 + dsel];
    float acc = 0.f;
#pragma unroll
    for (int e = 0; e < 64; ++e) acc = fmaf(xs[w][e], wc[e], acc);
    float y = acc + boc + query[r * 64 + lane];
    float mean = wave_sum(y) * 0.015625f;
    float d = y - mean;
    float var = wave_sum(d * d) * 0.015625f;
    float v = d * rsqrtf(var + LN_EPS) * gc + bc;
    xout[r * 64 + lane] = v;
    xbf[r * 64 + lane] = f2b(v);
  }
}

// ---------------------------------------------------------------------------
// proj_bf_split: blocked bf16 hi/lo of (in @ W^T).
// Bh/Bl[(mt*4096 + t*64 + c)*16 + (m&15)], split hi+lo for precision.
// ---------------------------------------------------------------------------
__global__ __launch_bounds__(256) void proj_bf_split(
    const float* __restrict__ in, const float* __restrict__ W,
    unsigned short* __restrict__ Bh, unsigned short* __restrict__ Bl) {
  __shared__ float xs[4][64];
  __shared__ float Ls[4][16][68];
  const int tid = threadIdx.x, lane = tid & 63, w = tid >> 6;
  const int mt = blockIdx.x;
  const int t = blockIdx.y * 4 + w;
  float wc[64];
#pragma unroll
  for (int e = 0; e < 16; ++e)
    *(float4*)&wc[e * 4] = *(const float4*)&W[lane * 64 + e * 4];
#pragma unroll 4
  for (int ms = 0; ms < 16; ++ms) {
    const int r = (mt * 16 + ms) * 64 + t;
    xs[w][lane] = in[r * 64 + lane];
    float acc = 0.f;
#pragma unroll
    for (int e = 0; e < 64; ++e) acc = fmaf(xs[w][e], wc[e], acc);
    Ls[w][ms][lane] = acc;
  }
  unsigned int dh[8], dl[8];
#pragma unroll
  for (int j = 0; j < 8; ++j) {
    float v0 = Ls[w][2 * j][lane];
    float v1 = Ls[w][2 * j + 1][lane];
    unsigned int h0 = f2b(v0), h1 = f2b(v1);
    unsigned int l0 = f2b(v0 - b2f(h0)), l1 = f2b(v1 - b2f(h1));
    dh[j] = h0 | (h1 << 16);
    dl[j] = l0 | (l1 << 16);
  }
  const int off = ((mt * 4096) + t * 64 + lane) * 16;
  *(uint4*)(Bh + off) = *(uint4*)&dh[0];
  *(uint4*)(Bh + off + 8) = *(uint4*)&dh[4];
  *(uint4*)(Bl + off) = *(uint4*)&dl[0];
  *(uint4*)(Bl + off + 8) = *(uint4*)&dl[4];
}

// ---------------------------------------------------------------------------
// Generic zero-LDS MFMA GEMM (FFN path): out = A(bf16) @ Bf + bias
// EPI: 2 = bias+relu->bf16, 3 = bias+resid+LN->f32 (N==64, NW==1).
// ---------------------------------------------------------------------------
template <int N, int K, int MW, int NW, int EPI>
__global__ __launch_bounds__(256) void mfma_gemm(
    const unsigned short* __restrict__ A, const unsigned short* __restrict__ Bf,
    const float* __restrict__ bias, const float* __restrict__ resid,
    const float* __restrict__ gamma, const float* __restrict__ beta,
    void* __restrict__ outv) {
  const int tid = threadIdx.x;
  const int wave = tid >> 6, lane = tid & 63;
  const int ln = lane & 15, quad = lane >> 4;
  const int wm = (wave % MW) * 32, wn = (wave / MW) * 64;
  const int m0 = blockIdx.y * (MW * 32) + wm;
  const int n0 = blockIdx.x * (NW * 64) + wn;

  const unsigned short* a0p = A + (m0 + ln) * K + quad * 4;
  const unsigned short* a1p = a0p + 16 * K;
  const unsigned short* bp = Bf + (n0 + ln) * 16 + quad * 4;

  float4v acc[2][4];
#pragma unroll
  for (int i = 0; i < 2; ++i)
#pragma unroll
    for (int j = 0; j < 4; ++j) {
      acc[i][j].x = 0.f; acc[i][j].y = 0.f;
      acc[i][j].z = 0.f; acc[i][j].w = 0.f;
    }

#pragma unroll 4
  for (int kt = 0; kt < K / 16; ++kt) {
    short4v a0 = *(const short4v*)(a0p + kt * 16);
    short4v a1 = *(const short4v*)(a1p + kt * 16);
#pragma unroll
    for (int j = 0; j < 4; ++j) {
      short4v b = *(const short4v*)(bp + (kt * N + j * 16) * 16);
      acc[0][j] = mfma_16x16x16_bf16(a0, b, acc[0][j]);
      acc[1][j] = mfma_16x16x16_bf16(a1, b, acc[1][j]);
    }
  }

  if (EPI == 3) {
    float* out = (float*)outv;
#pragma unroll
    for (int mt = 0; mt < 2; ++mt) {
#pragma unroll
      for (int reg = 0; reg < 4; ++reg) {
        const int row = m0 + mt * 16 + quad * 4 + reg;
        float v[4];
        float s = 0.f;
#pragma unroll
        for (int j = 0; j < 4; ++j) {
          v[j] = acc[mt][j][reg] + bias[j * 16 + ln] +
                 resid[row * 64 + j * 16 + ln];
          s += v[j];
        }
        s += __shfl_xor(s, 1, 64);
        s += __shfl_xor(s, 2, 64);
        s += __shfl_xor(s, 4, 64);
        s += __shfl_xor(s, 8, 64);
        const float mean = s * 0.015625f;
        float vv = 0.f;
#pragma unroll
        for (int j = 0; j < 4; ++j) {
          const float dd = v[j] - mean;
          vv += dd * dd;
        }
        vv += __shfl_xor(vv, 1, 64);
        vv += __shfl_xor(vv, 2, 64);
        vv += __shfl_xor(vv, 4, 64);
        vv += __shfl_xor(vv, 8, 64);
        const float rs = rsqrtf(vv * 0.015625f + LN_EPS);
#pragma unroll
        for (int j = 0; j < 4; ++j)
          out[row * 64 + j * 16 + ln] =
              (v[j] - mean) * rs * gamma[j * 16 + ln] + beta[j * 16 + ln];
      }
    }
  } else {
#pragma unroll
    for (int mt = 0; mt < 2; ++mt) {
#pragma unroll
      for (int j = 0; j < 4; ++j) {
        const int col = n0 + j * 16 + ln;
        const float b = bias[col];
#pragma unroll
        for (int reg = 0; reg < 4; ++reg) {
          const int row = m0 + mt * 16 + quad * 4 + reg;
          float v = fmaxf(acc[mt][j][reg] + b, 0.f);
          ((unsigned short*)outv)[row * N + col] = f2b(v);
        }
      }
    }
  }
}

// ---------------------------------------------------------------------------
// Split-precision MFMA GEMM for the adjacency GCN:
// out[512][4096] = (Ah+Al)[512][512] @ (Bh+Bl) + bias[col&63]
// acc = ah*bh + ah*bl + al*bh  (lo*lo dropped, ~2^-18 rel).
// grid (32, 8), block 256: wave tile 32m x 64n, block tile 64m x 128n.
// EPI: 0 = relu -> f32, 1 = none -> f32.
// ---------------------------------------------------------------------------
template <int EPI>
__global__ __launch_bounds__(256) void mfma_gemm_split(
    const unsigned short* __restrict__ Ah, const unsigned short* __restrict__ Al,
    const unsigned short* __restrict__ Bh, const unsigned short* __restrict__ Bl,
    const float* __restrict__ bias, float* __restrict__ out) {
  const int tid = threadIdx.x;
  const int wave = tid >> 6, lane = tid & 63;
  const int ln = lane & 15, quad = lane >> 4;
  const int wm = (wave & 1) * 32, wn = (wave >> 1) * 64;
  const int m0 = blockIdx.y * 64 + wm;
  const int n0 = blockIdx.x * 128 + wn;

  const unsigned short* ah0 = Ah + (m0 + ln) * 512 + quad * 4;
  const unsigned short* al0 = Al + (m0 + ln) * 512 + quad * 4;
  const unsigned short* bh0 = Bh + (n0 + ln) * 16 + quad * 4;
  const unsigned short* bl0 = Bl + (n0 + ln) * 16 + quad * 4;

  float4v acc[2][4];
#pragma unroll
  for (int i = 0; i < 2; ++i)
#pragma unroll
    for (int j = 0; j < 4; ++j) {
      acc[i][j].x = 0.f; acc[i][j].y = 0.f;
      acc[i][j].z = 0.f; acc[i][j].w = 0.f;
    }

#pragma unroll 2
  for (int kt = 0; kt < 32; ++kt) {
    short4v a0h = *(const short4v*)(ah0 + kt * 16);
    short4v a1h = *(const short4v*)(ah0 + 16 * 512 + kt * 16);
    short4v a0l = *(const short4v*)(al0 + kt * 16);
    short4v a1l = *(const short4v*)(al0 + 16 * 512 + kt * 16);
#pragma unroll
    for (int j = 0; j < 4; ++j) {
      const int boff = (kt * 4096 + j * 16) * 16;
      short4v bh = *(const short4v*)(bh0 + boff);
      short4v bl = *(const short4v*)(bl0 + boff);
      acc[0][j] = mfma_16x16x16_bf16(a0l, bh, acc[0][j]);
      acc[0][j] = mfma_16x16x16_bf16(a0h, bl, acc[0][j]);
      acc[0][j] = mfma_16x16x16_bf16(a0h, bh, acc[0][j]);
      acc[1][j] = mfma_16x16x16_bf16(a1l, bh, acc[1][j]);
      acc[1][j] = mfma_16x16x16_bf16(a1h, bl, acc[1][j]);
      acc[1][j] = mfma_16x16x16_bf16(a1h, bh, acc[1][j]);
    }
  }

#pragma unroll
  for (int mt = 0; mt < 2; ++mt) {
#pragma unroll
    for (int j = 0; j < 4; ++j) {
      const int col = n0 + j * 16 + ln;
      const float b = bias[col & 63];
#pragma unroll
      for (int reg = 0; reg < 4; ++reg) {
        const int row = m0 + mt * 16 + quad * 4 + reg;
        float v = acc[mt][j][reg] + b;
        if (EPI == 0) v = fmaxf(v, 0.f);
        out[row * 4096 + col] = v;
      }
    }
  }
}

// ---------------------------------------------------------------------------
// weight repack: Bf[((k>>4)*N + n)*16 + (k&15)] = bf16(W[n][k])
// ---------------------------------------------------------------------------
template <int N, int K>
__global__ __launch_bounds__(256) void wrepack(const float* __restrict__ W,
                                               unsigned short* __restrict__ Bf) {
  const int id = blockIdx.x * 256 + threadIdx.x;
  const int n = id / K, k = id % K;
  Bf[((k >> 4) * N + n) * 16 + (k & 15)] = f2b(W[id]);
}

// ---------------------------------------------------------------------------
// adj mean/var + split-normalize to bf16 hi/lo
// ---------------------------------------------------------------------------
__global__ __launch_bounds__(256) void adj_part(const float* __restrict__ adj,
                                                float* __restrict__ ps,
                                                float* __restrict__ pss) {
  __shared__ float r1[4], r2[4];
  const int b = blockIdx.x, tid = threadIdx.x;
  float v0 = adj[b * 512 + tid], v1 = adj[b * 512 + 256 + tid];
  float s = v0 + v1;
  float ss = fmaf(v0, v0, v1 * v1);
  s = wave_sum(s);
  ss = wave_sum(ss);
  if ((tid & 63) == 0) { r1[tid >> 6] = s; r2[tid >> 6] = ss; }
  __syncthreads();
  if (tid == 0) {
    ps[b] = r1[0] + r1[1] + r1[2] + r1[3];
    pss[b] = r2[0] + r2[1] + r2[2] + r2[3];
  }
}

__global__ __launch_bounds__(256) void adj_fin(const float* __restrict__ ps,
                                               const float* __restrict__ pss,
                                               float* __restrict__ stats) {
  __shared__ float r1[4], r2[4];
  const int tid = threadIdx.x;
  float s = ps[tid] + ps[tid + 256];
  float ss = pss[tid] + pss[tid + 256];
  s = wave_sum(s);
  ss = wave_sum(ss);
  if ((tid & 63) == 0) { r1[tid >> 6] = s; r2[tid >> 6] = ss; }
  __syncthreads();
  if (tid == 0) {
    stats[0] = r1[0] + r1[1] + r1[2] + r1[3];
    stats[1] = r2[0] + r2[1] + r2[2] + r2[3];
  }
}

__global__ __launch_bounds__(256) void adj_norm_split(
    const float* __restrict__ adj, const float* __restrict__ stats,
    unsigned short* __restrict__ anh, unsigned short* __restrict__ anl) {
  const float am = stats[0] * (1.f / 262144.f);
  const float var = stats[1] * (1.f / 262144.f) - am * am;
  const float rs = rsqrtf(var + LN_EPS);
  const int i = (blockIdx.x * 256 + threadIdx.x) * 4;
  float4 v = *(const float4*)&adj[i];
  float vals[4] = {(v.x - am) * rs, (v.y - am) * rs, (v.z - am) * rs,
                   (v.w - am) * rs};
  unsigned short th[4], tl[4];
#pragma unroll
  for (int j = 0; j < 4; ++j) {
    th[j] = f2b(vals[j]);
    tl[j] = f2b(vals[j] - b2f(th[j]));
  }
  *(short4v*)&anh[i] = *(short4v*)th;
  *(short4v*)&anl[i] = *(short4v*)tl;
}

// ---------------------------------------------------------------------------
// J: gated fusion -> d_out
// ---------------------------------------------------------------------------
__global__ __launch_bounds__(256) void row_gate(
    const float* __restrict__ out1, const float* __restrict__ out2,
    const float* __restrict__ Wo1, const float* __restrict__ Wo2,
    const float* __restrict__ bo1, const float* __restrict__ bo2,
    float* __restrict__ dst) {
  __shared__ float xs1[4][64], xs2[4][64];
  const int tid = threadIdx.x, lane = tid & 63, w = tid >> 6;
  float w1[64], w2[64];
#pragma unroll
  for (int e = 0; e < 16; ++e) {
    *(float4*)&w1[e * 4] = *(const float4*)&Wo1[lane * 64 + e * 4];
    *(float4*)&w2[e * 4] = *(const float4*)&Wo2[lane * 64 + e * 4];
  }
  const float bsum = bo1[lane] + bo2[lane];
  const int r0 = blockIdx.x * 16 + w * 4;
  for (int it = 0; it < 4; ++it) {
    const int r = r0 + it;
    float o1 = out1[r * 64 + lane];
    float o2 = out2[r * 64 + lane];
    xs1[w][lane] = o1;
    xs2[w][lane] = o2;
    float acc = bsum;
#pragma unroll
    for (int e = 0; e < 64; ++e) {
      acc = fmaf(xs1[w][e], w1[e], acc);
      acc = fmaf(xs2[w][e], w2[e], acc);
    }
    float g = 1.f / (1.f + __expf(-acc));
    dst[r * 64 + lane] = o2 + g * (o1 - o2);
  }
}

// ---------------------------------------------------------------------------
extern "C" void kernel_launch(void* const* d_in, const int* in_sizes, int n_in,
                              void* d_out, int out_size, void* d_ws,
                              size_t ws_size, hipStream_t stream) {
  const float* value = (const float*)d_in[0];
  const float* key_t = (const float*)d_in[1];
  const float* query = (const float*)d_in[2];
  const float* adj = (const float*)d_in[3];
  const float* Wv = (const float*)d_in[4];
  const float* Wk = (const float*)d_in[5];
  const float* Wq = (const float*)d_in[6];
  const float* Wo = (const float*)d_in[7];
  const float* bo = (const float*)d_in[8];
  const float* g1 = (const float*)d_in[9];
  const float* b1 = (const float*)d_in[10];
  const float* g2 = (const float*)d_in[11];
  const float* b2 = (const float*)d_in[12];
  const float* Wf1 = (const float*)d_in[13];
  const float* bf1 = (const float*)d_in[14];
  const float* Wf2 = (const float*)d_in[15];
  const float* bf2 = (const float*)d_in[16];
  const float* Wg1 = (const float*)d_in[17];
  const float* bg1 = (const float*)d_in[18];
  const float* Wg2 = (const float*)d_in[19];
  const float* bg2 = (const float*)d_in[20];
  const float* Wo1 = (const float*)d_in[21];
  const float* bo1 = (const float*)d_in[22];
  const float* Wo2 = (const float*)d_in[23];
  const float* bo2 = (const float*)d_in[24];

  float* ws = (float*)d_ws;
  const size_t M1 = 1048576;
  unsigned short* qh = (unsigned short*)(ws + 0);           // [0,1M)
  unsigned short* kh = (unsigned short*)(ws + 1 * M1);      // [1M,2M)
  unsigned short* vt = (unsigned short*)(ws + 2 * M1);      // [2M,3M)
  float* o = ws + 3 * M1;                                   // [3M,5M)
  float* x = ws + 5 * M1;                                   // [5M,7M)
  unsigned short* xbf = (unsigned short*)(ws + 7 * M1);     // [7M,8M)
  unsigned short* hid = (unsigned short*)(ws + 8 * M1);     // [8M,12M)
  unsigned short* Yfh = (unsigned short*)(ws + 12 * M1);    // [12M,13M)
  unsigned short* Yfl = (unsigned short*)(ws + 13 * M1);    // [13M,14M)
  unsigned short* anh = (unsigned short*)(ws + 14 * M1);    // 512KB
  unsigned short* anl = (unsigned short*)(ws + 14 * M1 + 131072);
  unsigned short* Wf1f = (unsigned short*)(ws + 14 * M1 + 262144);
  unsigned short* Wf2f = (unsigned short*)(ws + 14 * M1 + 262144 + 8192);
  float* Z = ws + 15 * M1;                                  // [15M,17M)
  unsigned short* H2fh = (unsigned short*)(ws + 17 * M1);   // [17M,18M)
  unsigned short* H2fl = (unsigned short*)(ws + 18 * M1);   // [18M,19M)
  float* out2 = ws + 19 * M1;                               // [19M,21M)
  float* out1 = ws + 21 * M1;                               // [21M,23M)
  float* stats = ws + 23 * M1;
  float* ps = stats + 4;
  float* pss = ps + 512;
  float* dst = (float*)d_out;

  // GCN prep (independent chain)
  adj_part<<<512, 256, 0, stream>>>(adj, ps, pss);
  adj_fin<<<1, 256, 0, stream>>>(ps, pss, stats);
  adj_norm_split<<<256, 256, 0, stream>>>(adj, stats, anh, anl);
  wrepack<256, 64><<<64, 256, 0, stream>>>(Wf1, Wf1f);
  wrepack<64, 256><<<64, 256, 0, stream>>>(Wf2, Wf2f);

  // attention chain
  qkv2_kernel<<<256, 512, 0, stream>>>(value, key_t, query, Wv, Wk, Wq, vt, kh, qh);
  attn_mfma<<<512, 256, 0, stream>>>(qh, kh, vt, o);
  row_wo_ln<<<2048, 256, 0, stream>>>(o, query, Wo, bo, g1, b1, x, xbf);
  // FFN1: hid = relu(x @ Wf1^T + bf1), bf16 out
  mfma_gemm<256, 64, 2, 2, 2><<<dim3(2, 512), 256, 0, stream>>>(
      xbf, Wf1f, bf1, nullptr, nullptr, nullptr, (void*)hid);
  // FFN2 + LN2: out1 = LN2(hid @ Wf2^T + bf2 + x)
  mfma_gemm<64, 256, 4, 1, 3><<<dim3(1, 256), 256, 0, stream>>>(
      hid, Wf2f, bf2, x, g2, b2, (void*)out1);

  // GCN chain (split precision)
  proj_bf_split<<<dim3(32, 16), 256, 0, stream>>>(query, Wg1, Yfh, Yfl);
  mfma_gemm_split<0><<<dim3(32, 8), 256, 0, stream>>>(anh, anl, Yfh, Yfl, bg1, Z);
  proj_bf_split<<<dim3(32, 16), 256, 0, stream>>>(Z, Wg2, H2fh, H2fl);
  mfma_gemm_split<1><<<dim3(32, 8), 256, 0, stream>>>(anh, anl, H2fh, H2fl, bg2, out2);

  // gated fusion
  row_gate<<<2048, 256, 0, stream>>>(out1, out2, Wo1, Wo2, bo1, bo2, dst);
}

// Round 5
// 318.058 us; speedup vs baseline: 1.4338x; 1.0623x over previous
//
#include <hip/hip_runtime.h>

#define LN_EPS 1e-5f

typedef __attribute__((ext_vector_type(4))) short short4v;
typedef __attribute__((ext_vector_type(4))) float float4v;

__device__ __forceinline__ float wave_sum(float v) {
#pragma unroll
  for (int o = 32; o > 0; o >>= 1) v += __shfl_xor(v, o, 64);
  return v;
}

// round-to-nearest-even f32 -> bf16
__device__ __forceinline__ unsigned short f2b(float f) {
  unsigned int u = __float_as_uint(f);
  u += 0x7fffu + ((u >> 16) & 1u);
  return (unsigned short)(u >> 16);
}

__device__ __forceinline__ float b2f(unsigned short h) {
  return __uint_as_float(((unsigned int)h) << 16);
}

__device__ __forceinline__ float4v mfma_16x16x16_bf16(short4v a, short4v b,
                                                      float4v c) {
#if __has_builtin(__builtin_amdgcn_mfma_f32_16x16x16bf16_1k)
  return __builtin_amdgcn_mfma_f32_16x16x16bf16_1k(a, b, c, 0, 0, 0);
#else
  float4v d;
  asm volatile(
      "v_mfma_f32_16x16x16_bf16 %0, %1, %2, %3\n\ts_nop 7\n\ts_nop 7"
      : "=v"(d)
      : "v"(a), "v"(b), "v"(c));
  return d;
#endif
}

// ---------------------------------------------------------------------------
// K1: adj row partial sums
// ---------------------------------------------------------------------------
__global__ __launch_bounds__(256) void adj_part(const float* __restrict__ adj,
                                                float* __restrict__ ps,
                                                float* __restrict__ pss) {
  __shared__ float r1[4], r2[4];
  const int b = blockIdx.x, tid = threadIdx.x;
  float v0 = adj[b * 512 + tid], v1 = adj[b * 512 + 256 + tid];
  float s = v0 + v1;
  float ss = fmaf(v0, v0, v1 * v1);
  s = wave_sum(s);
  ss = wave_sum(ss);
  if ((tid & 63) == 0) { r1[tid >> 6] = s; r2[tid >> 6] = ss; }
  __syncthreads();
  if (tid == 0) {
    ps[b] = r1[0] + r1[1] + r1[2] + r1[3];
    pss[b] = r2[0] + r2[1] + r2[2] + r2[3];
  }
}

// ---------------------------------------------------------------------------
// K2: prep — block-dispatched fusion:
//  [0,256)   adj stats (redundant reduce) + split-normalize slice
//  [256,320) wrepack Wf1 (N=256,K=64)
//  [320,384) wrepack Wf2 (N=64,K=256)
//  [384,896) proj_bf_split(query @ Wg1^T) -> Yfh/Yfl blocked
// ---------------------------------------------------------------------------
__global__ __launch_bounds__(256) void prep_kernel(
    const float* __restrict__ adj, const float* __restrict__ ps,
    const float* __restrict__ pss, const float* __restrict__ query,
    const float* __restrict__ Wg1, const float* __restrict__ Wf1,
    const float* __restrict__ Wf2, unsigned short* __restrict__ anh,
    unsigned short* __restrict__ anl, unsigned short* __restrict__ Yfh,
    unsigned short* __restrict__ Yfl, unsigned short* __restrict__ Wf1f,
    unsigned short* __restrict__ Wf2f) {
  __shared__ float r1[4], r2[4];
  __shared__ float xs[4][64];
  __shared__ float Ls[4][16][68];
  const int tid = threadIdx.x, b = blockIdx.x;
  if (b < 256) {
    float s = ps[tid] + ps[tid + 256];
    float ss = pss[tid] + pss[tid + 256];
    s = wave_sum(s);
    ss = wave_sum(ss);
    if ((tid & 63) == 0) { r1[tid >> 6] = s; r2[tid >> 6] = ss; }
    __syncthreads();
    const float sum = r1[0] + r1[1] + r1[2] + r1[3];
    const float sqs = r2[0] + r2[1] + r2[2] + r2[3];
    const float am = sum * (1.f / 262144.f);
    const float var = sqs * (1.f / 262144.f) - am * am;
    const float rs = rsqrtf(var + LN_EPS);
    const int i = (b * 256 + tid) * 4;
    float4 v = *(const float4*)&adj[i];
    float vals[4] = {(v.x - am) * rs, (v.y - am) * rs, (v.z - am) * rs,
                     (v.w - am) * rs};
    unsigned short th[4], tl[4];
#pragma unroll
    for (int j = 0; j < 4; ++j) {
      th[j] = f2b(vals[j]);
      tl[j] = f2b(vals[j] - b2f(th[j]));
    }
    *(short4v*)&anh[i] = *(short4v*)th;
    *(short4v*)&anl[i] = *(short4v*)tl;
  } else if (b < 320) {
    const int id = (b - 256) * 256 + tid;
    const int n = id >> 6, k = id & 63;
    Wf1f[((k >> 4) * 256 + n) * 16 + (k & 15)] = f2b(Wf1[id]);
  } else if (b < 384) {
    const int id = (b - 320) * 256 + tid;
    const int n = id >> 8, k = id & 255;
    Wf2f[((k >> 4) * 64 + n) * 16 + (k & 15)] = f2b(Wf2[id]);
  } else {
    const int pb = b - 384;
    const int w = tid >> 6, lane = tid & 63;
    const int mt = pb & 31;
    const int t = (pb >> 5) * 4 + w;
    float wc[64];
#pragma unroll
    for (int e = 0; e < 16; ++e)
      *(float4*)&wc[e * 4] = *(const float4*)&Wg1[lane * 64 + e * 4];
#pragma unroll 4
    for (int ms = 0; ms < 16; ++ms) {
      const int r = (mt * 16 + ms) * 64 + t;
      xs[w][lane] = query[r * 64 + lane];
      float acc = 0.f;
#pragma unroll
      for (int e = 0; e < 64; ++e) acc = fmaf(xs[w][e], wc[e], acc);
      Ls[w][ms][lane] = acc;
    }
    unsigned int dh[8], dl[8];
#pragma unroll
    for (int j = 0; j < 8; ++j) {
      float v0 = Ls[w][2 * j][lane];
      float v1 = Ls[w][2 * j + 1][lane];
      unsigned int h0 = f2b(v0), h1 = f2b(v1);
      unsigned int l0 = f2b(v0 - b2f((unsigned short)h0));
      unsigned int l1 = f2b(v1 - b2f((unsigned short)h1));
      dh[j] = h0 | (h1 << 16);
      dl[j] = l0 | (l1 << 16);
    }
    const int off = ((mt * 4096) + t * 64 + lane) * 16;
    *(uint4*)(Yfh + off) = *(uint4*)&dh[0];
    *(uint4*)(Yfh + off + 8) = *(uint4*)&dh[4];
    *(uint4*)(Yfl + off) = *(uint4*)&dl[0];
    *(uint4*)(Yfl + off + 8) = *(uint4*)&dl[4];
  }
}

// ---------------------------------------------------------------------------
// K3: fused QKV + MFMA attention. grid 512 (2 blocks per th), 256 thr.
// Stage 1: QKV projections straight into LDS (K/V full 512 nodes, Q this
// half's 256). Stage 2: verified S^T=K@Q^T -> exp -> O^T=V^T@P^T loop.
// ---------------------------------------------------------------------------
#define KSTR 24
#define VPAD 536
__global__ __launch_bounds__(256) void attn_fused(
    const float* __restrict__ value, const float* __restrict__ keyt,
    const float* __restrict__ query, const float* __restrict__ Wv,
    const float* __restrict__ Wk, const float* __restrict__ Wq,
    float* __restrict__ o) {
  __shared__ __align__(16) float wv[256], wk[256], wq[256];
  __shared__ __align__(16) unsigned short Ks[512 * KSTR];
  __shared__ __align__(16) unsigned short Qs[256 * KSTR];
  __shared__ __align__(16) unsigned short Vs[16 * VPAD];
  const int tid = threadIdx.x;
  const int th = blockIdx.x >> 1;
  const int half = blockIdx.x & 1;
  wv[tid] = Wv[tid];
  wk[tid] = Wk[tid];
  wq[tid] = Wq[tid] * 0.125f;
  __syncthreads();
  const int t = th >> 2, h = th & 3;
  const int base = t * 64 + h * 16;

#define XF(SRC, WARR)                                               \
  {                                                                 \
    const float4* p = (const float4*)(SRC + n * 4096 + base);       \
    float xr[16];                                                   \
    *(float4*)(xr + 0) = p[0];                                      \
    *(float4*)(xr + 4) = p[1];                                      \
    *(float4*)(xr + 8) = p[2];                                      \
    *(float4*)(xr + 12) = p[3];                                     \
    _Pragma("unroll") for (int d = 0; d < 16; ++d) {                \
      float acc = 0.f;                                              \
      _Pragma("unroll") for (int e4 = 0; e4 < 4; ++e4) {            \
        float4 w4 = *(const float4*)&WARR[d * 16 + e4 * 4];         \
        acc = fmaf(w4.x, xr[e4 * 4 + 0], acc);                      \
        acc = fmaf(w4.y, xr[e4 * 4 + 1], acc);                      \
        acc = fmaf(w4.z, xr[e4 * 4 + 2], acc);                      \
        acc = fmaf(w4.w, xr[e4 * 4 + 3], acc);                      \
      }                                                             \
      y[d] = acc;                                                   \
    }                                                               \
  }

  for (int s = 0; s < 2; ++s) {
    const int n = tid + (s << 8);
    float y[16];
    unsigned short tmp[16];
    // K
    XF(keyt, wk)
#pragma unroll
    for (int d = 0; d < 16; ++d) tmp[d] = f2b(y[d]);
    *(int4*)&Ks[n * KSTR] = *(int4*)&tmp[0];
    *(int4*)&Ks[n * KSTR + 8] = *(int4*)&tmp[8];
    // V (transposed)
    XF(value, wv)
#pragma unroll
    for (int d = 0; d < 16; ++d) Vs[d * VPAD + n] = f2b(y[d]);
    // Q only for this half's nodes
    if (s == half) {
      XF(query, wq)
#pragma unroll
      for (int d = 0; d < 16; ++d) tmp[d] = f2b(y[d]);
      *(int4*)&Qs[tid * KSTR] = *(int4*)&tmp[0];
      *(int4*)&Qs[tid * KSTR + 8] = *(int4*)&tmp[8];
    }
  }
#undef XF
  __syncthreads();

  const int lane = tid & 15;
  const int quad = (tid >> 4) & 3;
  const int w = tid >> 6;

  short4v qf[4];
#pragma unroll
  for (int ct = 0; ct < 4; ++ct)
    qf[ct] = *(const short4v*)&Qs[(w * 64 + ct * 16 + lane) * KSTR + quad * 4];

  float4v acc[4];
  float l[4];
#pragma unroll
  for (int ct = 0; ct < 4; ++ct) {
    acc[ct].x = 0.f; acc[ct].y = 0.f; acc[ct].z = 0.f; acc[ct].w = 0.f;
    l[ct] = 0.f;
  }
  float4v zero;
  zero.x = 0.f; zero.y = 0.f; zero.z = 0.f; zero.w = 0.f;

  const unsigned short* vrow = &Vs[lane * VPAD];

  for (int kt = 0; kt < 32; ++kt) {
    const short4v kf =
        *(const short4v*)&Ks[(kt * 16 + lane) * KSTR + quad * 4];
    const short4v vf = *(const short4v*)&vrow[kt * 16 + quad * 4];
#pragma unroll
    for (int ct = 0; ct < 4; ++ct) {
      float4v s = mfma_16x16x16_bf16(kf, qf[ct], zero);
      float p0 = __expf(s.x);
      float p1 = __expf(s.y);
      float p2 = __expf(s.z);
      float p3 = __expf(s.w);
      l[ct] += (p0 + p1) + (p2 + p3);
      unsigned int u0 = __float_as_uint(p0) + 0x8000u;
      unsigned int u1 = __float_as_uint(p1) + 0x8000u;
      unsigned int u2 = __float_as_uint(p2) + 0x8000u;
      unsigned int u3 = __float_as_uint(p3) + 0x8000u;
      union {
        uint2 u;
        short4v s4;
      } pk;
      pk.u.x = __builtin_amdgcn_perm(u1, u0, 0x07060302u);
      pk.u.y = __builtin_amdgcn_perm(u3, u2, 0x07060302u);
      acc[ct] = mfma_16x16x16_bf16(vf, pk.s4, acc[ct]);
    }
  }

#pragma unroll
  for (int ct = 0; ct < 4; ++ct) {
    float lt = l[ct];
    lt += __shfl_xor(lt, 16, 64);
    lt += __shfl_xor(lt, 32, 64);
    const float inv = 1.f / lt;
    float4 out;
    out.x = acc[ct].x * inv;
    out.y = acc[ct].y * inv;
    out.z = acc[ct].z * inv;
    out.w = acc[ct].w * inv;
    const int q = (half << 8) + w * 64 + ct * 16 + lane;
    *(float4*)&o[th * 8192 + q * 16 + quad * 4] = out;
  }
}

// ---------------------------------------------------------------------------
// K4: fused Wo-proj + LN1 + FFN1 + FFN2 + LN2 -> out1. grid 512 (one n
// each, rows t=0..63), 256 thr.
// ---------------------------------------------------------------------------
__global__ __launch_bounds__(256) void xffn_fused(
    const float* __restrict__ o, const float* __restrict__ query,
    const float* __restrict__ Wo, const float* __restrict__ bo,
    const float* __restrict__ g1, const float* __restrict__ b1,
    const unsigned short* __restrict__ Wf1f, const float* __restrict__ bf1,
    const unsigned short* __restrict__ Wf2f, const float* __restrict__ bf2,
    const float* __restrict__ g2, const float* __restrict__ b2,
    float* __restrict__ out1) {
  __shared__ float xs_res[64][68];
  __shared__ __align__(16) unsigned short xb[64 * 68];
  __shared__ __align__(16) unsigned short hid[64 * 260];
  __shared__ float bcast[4][64];
  const int tid = threadIdx.x;
  const int w = tid >> 6, lane = tid & 63;
  const int ln = lane & 15, quad = lane >> 4;
  const int n = blockIdx.x;

  // ---- Phase A: x = LN1(o @ Wo^T + bo + query)
  {
    float wc[64];
#pragma unroll
    for (int e = 0; e < 16; ++e)
      *(float4*)&wc[e * 4] = *(const float4*)&Wo[lane * 64 + e * 4];
    const float boc = bo[lane], gc = g1[lane], bc1 = b1[lane];
    const int hsel = lane >> 4, dsel = lane & 15;
    for (int i = 0; i < 16; ++i) {
      const int tt = w * 16 + i;
      bcast[w][lane] = o[(tt * 4 + hsel) * 8192 + n * 16 + dsel];
      float acc = 0.f;
#pragma unroll
      for (int e = 0; e < 64; ++e) acc = fmaf(bcast[w][e], wc[e], acc);
      float y = acc + boc + query[(n * 64 + tt) * 64 + lane];
      float mean = wave_sum(y) * 0.015625f;
      float d = y - mean;
      float var = wave_sum(d * d) * 0.015625f;
      float v = d * rsqrtf(var + LN_EPS) * gc + bc1;
      xs_res[tt][lane] = v;
      xb[tt * 68 + lane] = f2b(v);
    }
  }
  __syncthreads();

  // ---- Phase B: hid = relu(x @ Wf1^T + bf1) (bf16, LDS)
  {
    const int wm = (w & 1) * 32, wn = (w >> 1) * 128;
    float4v acc[2][8];
#pragma unroll
    for (int i = 0; i < 2; ++i)
#pragma unroll
      for (int j = 0; j < 8; ++j) {
        acc[i][j].x = 0.f; acc[i][j].y = 0.f;
        acc[i][j].z = 0.f; acc[i][j].w = 0.f;
      }
#pragma unroll
    for (int kt = 0; kt < 4; ++kt) {
      short4v a0 = *(const short4v*)&xb[(wm + ln) * 68 + kt * 16 + quad * 4];
      short4v a1 =
          *(const short4v*)&xb[(wm + 16 + ln) * 68 + kt * 16 + quad * 4];
#pragma unroll
      for (int j = 0; j < 8; ++j) {
        short4v bfr = *(const short4v*)&Wf1f[(kt * 256 + wn + j * 16 + ln) * 16 +
                                             quad * 4];
        acc[0][j] = mfma_16x16x16_bf16(a0, bfr, acc[0][j]);
        acc[1][j] = mfma_16x16x16_bf16(a1, bfr, acc[1][j]);
      }
    }
#pragma unroll
    for (int mt = 0; mt < 2; ++mt)
#pragma unroll
      for (int j = 0; j < 8; ++j) {
        const int col = wn + j * 16 + ln;
        const float bb = bf1[col];
#pragma unroll
        for (int reg = 0; reg < 4; ++reg) {
          const int row = wm + mt * 16 + quad * 4 + reg;
          hid[row * 260 + col] = f2b(fmaxf(acc[mt][j][reg] + bb, 0.f));
        }
      }
  }
  __syncthreads();

  // ---- Phase C: out1 = LN2(hid @ Wf2^T + bf2 + x)
  {
    float4v acc[4];
#pragma unroll
    for (int j = 0; j < 4; ++j) {
      acc[j].x = 0.f; acc[j].y = 0.f; acc[j].z = 0.f; acc[j].w = 0.f;
    }
#pragma unroll 4
    for (int kt = 0; kt < 16; ++kt) {
      short4v a =
          *(const short4v*)&hid[(w * 16 + ln) * 260 + kt * 16 + quad * 4];
#pragma unroll
      for (int j = 0; j < 4; ++j) {
        short4v bfr =
            *(const short4v*)&Wf2f[(kt * 64 + j * 16 + ln) * 16 + quad * 4];
        acc[j] = mfma_16x16x16_bf16(a, bfr, acc[j]);
      }
    }
#pragma unroll
    for (int reg = 0; reg < 4; ++reg) {
      const int row = w * 16 + quad * 4 + reg;
      float v[4];
      float s = 0.f;
#pragma unroll
      for (int j = 0; j < 4; ++j) {
        v[j] = acc[j][reg] + bf2[j * 16 + ln] + xs_res[row][j * 16 + ln];
        s += v[j];
      }
      s += __shfl_xor(s, 1, 64);
      s += __shfl_xor(s, 2, 64);
      s += __shfl_xor(s, 4, 64);
      s += __shfl_xor(s, 8, 64);
      const float mean = s * 0.015625f;
      float vv = 0.f;
#pragma unroll
      for (int j = 0; j < 4; ++j) {
        const float dd = v[j] - mean;
        vv += dd * dd;
      }
      vv += __shfl_xor(vv, 1, 64);
      vv += __shfl_xor(vv, 2, 64);
      vv += __shfl_xor(vv, 4, 64);
      vv += __shfl_xor(vv, 8, 64);
      const float rs = rsqrtf(vv * 0.015625f + LN_EPS);
#pragma unroll
      for (int j = 0; j < 4; ++j)
        out1[(n * 64 + row) * 64 + j * 16 + ln] =
            (v[j] - mean) * rs * g2[j * 16 + ln] + b2[j * 16 + ln];
    }
  }
}

// ---------------------------------------------------------------------------
// K5: split GEMM1 (adj_n @ Y) + relu + f32 proj with Wg2 + split-pack -> H2f
// grid (32,8), 256 thr. Wave tile 32m x 64n (one t per wave).
// ---------------------------------------------------------------------------
__global__ __launch_bounds__(256) void gcn_gemm1(
    const unsigned short* __restrict__ Ah, const unsigned short* __restrict__ Al,
    const unsigned short* __restrict__ Bh, const unsigned short* __restrict__ Bl,
    const float* __restrict__ bg1, const float* __restrict__ Wg2,
    unsigned short* __restrict__ H2fh, unsigned short* __restrict__ H2fl) {
  __shared__ float Ls[4][32 * 68];
  const int tid = threadIdx.x;
  const int wave = tid >> 6, lane = tid & 63;
  const int ln = lane & 15, quad = lane >> 4;
  const int wm = (wave & 1) * 32, wn = (wave >> 1) * 64;
  const int m0 = blockIdx.y * 64 + wm;
  const int n0 = blockIdx.x * 128 + wn;

  const unsigned short* ah0 = Ah + (m0 + ln) * 512 + quad * 4;
  const unsigned short* al0 = Al + (m0 + ln) * 512 + quad * 4;
  const unsigned short* bh0 = Bh + (n0 + ln) * 16 + quad * 4;
  const unsigned short* bl0 = Bl + (n0 + ln) * 16 + quad * 4;

  float4v acc[2][4];
#pragma unroll
  for (int i = 0; i < 2; ++i)
#pragma unroll
    for (int j = 0; j < 4; ++j) {
      acc[i][j].x = 0.f; acc[i][j].y = 0.f;
      acc[i][j].z = 0.f; acc[i][j].w = 0.f;
    }

#pragma unroll 2
  for (int kt = 0; kt < 32; ++kt) {
    short4v a0h = *(const short4v*)(ah0 + kt * 16);
    short4v a1h = *(const short4v*)(ah0 + 16 * 512 + kt * 16);
    short4v a0l = *(const short4v*)(al0 + kt * 16);
    short4v a1l = *(const short4v*)(al0 + 16 * 512 + kt * 16);
#pragma unroll
    for (int j = 0; j < 4; ++j) {
      const int boff = (kt * 4096 + j * 16) * 16;
      short4v bh = *(const short4v*)(bh0 + boff);
      short4v bl = *(const short4v*)(bl0 + boff);
      acc[0][j] = mfma_16x16x16_bf16(a0l, bh, acc[0][j]);
      acc[0][j] = mfma_16x16x16_bf16(a0h, bl, acc[0][j]);
      acc[0][j] = mfma_16x16x16_bf16(a0h, bh, acc[0][j]);
      acc[1][j] = mfma_16x16x16_bf16(a1l, bh, acc[1][j]);
      acc[1][j] = mfma_16x16x16_bf16(a1h, bl, acc[1][j]);
      acc[1][j] = mfma_16x16x16_bf16(a1h, bh, acc[1][j]);
    }
  }

  // epilogue: relu+bias -> wave-local LDS tile (rows = nodes, cols = c)
#pragma unroll
  for (int mt = 0; mt < 2; ++mt)
#pragma unroll
    for (int j = 0; j < 4; ++j) {
      const int c = j * 16 + ln;
      const float bb = bg1[c];
#pragma unroll
      for (int reg = 0; reg < 4; ++reg)
        Ls[wave][(mt * 16 + quad * 4 + reg) * 68 + c] =
            fmaxf(acc[mt][j][reg] + bb, 0.f);
    }

  // f32 projection with Wg2 (lane = output channel c')
  float wc[64];
#pragma unroll
  for (int e = 0; e < 16; ++e)
    *(float4*)&wc[e * 4] = *(const float4*)&Wg2[lane * 64 + e * 4];
  float hv[32];
#pragma unroll 2
  for (int r = 0; r < 32; ++r) {
    float a = 0.f;
#pragma unroll
    for (int e = 0; e < 64; ++e) a = fmaf(Ls[wave][r * 68 + e], wc[e], a);
    hv[r] = a;
  }

  // split-pack to blocked B layout for GEMM2
  const int tglob = blockIdx.x * 2 + (wn >> 6);
#pragma unroll
  for (int g = 0; g < 2; ++g) {
    const int mtout = (m0 + g * 16) >> 4;
    unsigned int dh[8], dl[8];
#pragma unroll
    for (int j = 0; j < 8; ++j) {
      float v0 = hv[g * 16 + 2 * j];
      float v1 = hv[g * 16 + 2 * j + 1];
      unsigned int h0 = f2b(v0), h1 = f2b(v1);
      unsigned int l0 = f2b(v0 - b2f((unsigned short)h0));
      unsigned int l1 = f2b(v1 - b2f((unsigned short)h1));
      dh[j] = h0 | (h1 << 16);
      dl[j] = l0 | (l1 << 16);
    }
    const int off = (mtout * 4096 + tglob * 64 + lane) * 16;
    *(uint4*)(H2fh + off) = *(uint4*)&dh[0];
    *(uint4*)(H2fh + off + 8) = *(uint4*)&dh[4];
    *(uint4*)(H2fl + off) = *(uint4*)&dl[0];
    *(uint4*)(H2fl + off + 8) = *(uint4*)&dl[4];
  }
}

// ---------------------------------------------------------------------------
// K6: split GEMM2 (adj_n @ H2) + bias + gated fusion with out1 -> dst
// ---------------------------------------------------------------------------
__global__ __launch_bounds__(256) void gcn_gemm2(
    const unsigned short* __restrict__ Ah, const unsigned short* __restrict__ Al,
    const unsigned short* __restrict__ Bh, const unsigned short* __restrict__ Bl,
    const float* __restrict__ bg2, const float* __restrict__ out1,
    const float* __restrict__ Wo1, const float* __restrict__ Wo2,
    const float* __restrict__ bo1, const float* __restrict__ bo2,
    float* __restrict__ dst) {
  __shared__ float Ls[4][32 * 68];
  __shared__ float bc[4][64];
  const int tid = threadIdx.x;
  const int wave = tid >> 6, lane = tid & 63;
  const int ln = lane & 15, quad = lane >> 4;
  const int wm = (wave & 1) * 32, wn = (wave >> 1) * 64;
  const int m0 = blockIdx.y * 64 + wm;
  const int n0 = blockIdx.x * 128 + wn;

  const unsigned short* ah0 = Ah + (m0 + ln) * 512 + quad * 4;
  const unsigned short* al0 = Al + (m0 + ln) * 512 + quad * 4;
  const unsigned short* bh0 = Bh + (n0 + ln) * 16 + quad * 4;
  const unsigned short* bl0 = Bl + (n0 + ln) * 16 + quad * 4;

  float4v acc[2][4];
#pragma unroll
  for (int i = 0; i < 2; ++i)
#pragma unroll
    for (int j = 0; j < 4; ++j) {
      acc[i][j].x = 0.f; acc[i][j].y = 0.f;
      acc[i][j].z = 0.f; acc[i][j].w = 0.f;
    }

#pragma unroll 2
  for (int kt = 0; kt < 32; ++kt) {
    short4v a0h = *(const short4v*)(ah0 + kt * 16);
    short4v a1h = *(const short4v*)(ah0 + 16 * 512 + kt * 16);
    short4v a0l = *(const short4v*)(al0 + kt * 16);
    short4v a1l = *(const short4v*)(al0 + 16 * 512 + kt * 16);
#pragma unroll
    for (int j = 0; j < 4; ++j) {
      const int boff = (kt * 4096 + j * 16) * 16;
      short4v bh = *(const short4v*)(bh0 + boff);
      short4v bl = *(const short4v*)(bl0 + boff);
      acc[0][j] = mfma_16x16x16_bf16(a0l, bh, acc[0][j]);
      acc[0][j] = mfma_16x16x16_bf16(a0h, bl, acc[0][j]);
      acc[0][j] = mfma_16x16x16_bf16(a0h, bh, acc[0][j]);
      acc[1][j] = mfma_16x16x16_bf16(a1l, bh, acc[1][j]);
      acc[1][j] = mfma_16x16x16_bf16(a1h, bl, acc[1][j]);
      acc[1][j] = mfma_16x16x16_bf16(a1h, bh, acc[1][j]);
    }
  }

  // stage out2 tile (rows = nodes, cols = c) into wave-local LDS
#pragma unroll
  for (int mt = 0; mt < 2; ++mt)
#pragma unroll
    for (int j = 0; j < 4; ++j) {
      const int c = j * 16 + ln;
      const float bb = bg2[c];
#pragma unroll
      for (int reg = 0; reg < 4; ++reg)
        Ls[wave][(mt * 16 + quad * 4 + reg) * 68 + c] = acc[mt][j][reg] + bb;
    }

  // gated fusion epilogue (row_gate numerics)
  float w1[64], w2[64];
#pragma unroll
  for (int e = 0; e < 16; ++e) {
    *(float4*)&w1[e * 4] = *(const float4*)&Wo1[lane * 64 + e * 4];
    *(float4*)&w2[e * 4] = *(const float4*)&Wo2[lane * 64 + e * 4];
  }
  const float bsum = bo1[lane] + bo2[lane];
  const int tglob = blockIdx.x * 2 + (wn >> 6);
  for (int r = 0; r < 32; ++r) {
    const int row = (m0 + r) * 64 + tglob;
    float o1 = out1[row * 64 + lane];
    bc[wave][lane] = o1;
    float o2 = Ls[wave][r * 68 + lane];
    float a = bsum;
#pragma unroll
    for (int e = 0; e < 64; ++e) {
      a = fmaf(bc[wave][e], w1[e], a);
      a = fmaf(Ls[wave][r * 68 + e], w2[e], a);
    }
    float g = 1.f / (1.f + __expf(-a));
    dst[row * 64 + lane] = o2 + g * (o1 - o2);
  }
}

// ---------------------------------------------------------------------------
extern "C" void kernel_launch(void* const* d_in, const int* in_sizes, int n_in,
                              void* d_out, int out_size, void* d_ws,
                              size_t ws_size, hipStream_t stream) {
  const float* value = (const float*)d_in[0];
  const float* key_t = (const float*)d_in[1];
  const float* query = (const float*)d_in[2];
  const float* adj = (const float*)d_in[3];
  const float* Wv = (const float*)d_in[4];
  const float* Wk = (const float*)d_in[5];
  const float* Wq = (const float*)d_in[6];
  const float* Wo = (const float*)d_in[7];
  const float* bo = (const float*)d_in[8];
  const float* g1 = (const float*)d_in[9];
  const float* b1 = (const float*)d_in[10];
  const float* g2 = (const float*)d_in[11];
  const float* b2 = (const float*)d_in[12];
  const float* Wf1 = (const float*)d_in[13];
  const float* bf1 = (const float*)d_in[14];
  const float* Wf2 = (const float*)d_in[15];
  const float* bf2 = (const float*)d_in[16];
  const float* Wg1 = (const float*)d_in[17];
  const float* bg1 = (const float*)d_in[18];
  const float* Wg2 = (const float*)d_in[19];
  const float* bg2 = (const float*)d_in[20];
  const float* Wo1 = (const float*)d_in[21];
  const float* bo1 = (const float*)d_in[22];
  const float* Wo2 = (const float*)d_in[23];
  const float* bo2 = (const float*)d_in[24];

  float* ws = (float*)d_ws;
  const size_t M1 = 1048576;
  float* o = ws + 0;                                       // [0,2M) f32
  float* out1 = ws + 2 * M1;                               // [2M,4M) f32
  unsigned short* Yfh = (unsigned short*)(ws + 4 * M1);    // 4MB
  unsigned short* Yfl = (unsigned short*)(ws + 5 * M1);    // 4MB
  unsigned short* H2fh = (unsigned short*)(ws + 6 * M1);   // 4MB
  unsigned short* H2fl = (unsigned short*)(ws + 7 * M1);   // 4MB
  unsigned short* anh = (unsigned short*)(ws + 8 * M1);    // 512KB
  unsigned short* anl = (unsigned short*)(ws + 8 * M1 + 131072);
  unsigned short* Wf1f = (unsigned short*)(ws + 8 * M1 + 262144);
  unsigned short* Wf2f = (unsigned short*)(ws + 8 * M1 + 262144 + 8192);
  float* ps = ws + 9 * M1;
  float* pss = ps + 512;
  float* dst = (float*)d_out;

  adj_part<<<512, 256, 0, stream>>>(adj, ps, pss);
  prep_kernel<<<896, 256, 0, stream>>>(adj, ps, pss, query, Wg1, Wf1, Wf2,
                                       anh, anl, Yfh, Yfl, Wf1f, Wf2f);
  attn_fused<<<512, 256, 0, stream>>>(value, key_t, query, Wv, Wk, Wq, o);
  xffn_fused<<<512, 256, 0, stream>>>(o, query, Wo, bo, g1, b1, Wf1f, bf1,
                                      Wf2f, bf2, g2, b2, out1);
  gcn_gemm1<<<dim3(32, 8), 256, 0, stream>>>(anh, anl, Yfh, Yfl, bg1, Wg2,
                                             H2fh, H2fl);
  gcn_gemm2<<<dim3(32, 8), 256, 0, stream>>>(anh, anl, H2fh, H2fl, bg2, out1,
                                             Wo1, Wo2, bo1, bo2, dst);
}